// Round 1
// baseline (1782.209 us; speedup 1.0000x reference)
//
#include <hip/hip_runtime.h>
#include <stdint.h>

#pragma clang fp contract(off)

#define NPRI   136500
#define BATCH  8
#define NMS_K  5000
#define TOPK   750
#define SORT_N 8192
#define HBINS  65536
#define SPAD   5120   // NMS_K padded to 1024*5

// -------- scores + histogram of top-16 bits --------
__global__ void score_hist_kernel(const float* __restrict__ conf,
                                  unsigned int* __restrict__ hist) {
    int p = blockIdx.x * 256 + threadIdx.x;
    int b = blockIdx.y;
    if (p >= NPRI) return;
    const float* c = conf + ((size_t)b * NPRI + p) * 2;
    float c0 = c[0], c1 = c[1];
    float m  = fmaxf(c0, c1);
    float e0 = expf(c0 - m), e1 = expf(c1 - m);
    float s  = e1 / (e0 + e1);
    if (s > 0.05f) {
        unsigned int bits = __float_as_uint(s);
        atomicAdd(&hist[b * HBINS + (bits >> 16)], 1u);
    }
}

// -------- find threshold bin t: count(bins >= t) >= NMS_K (or t=0) --------
__global__ void scan_kernel(const unsigned int* __restrict__ hist,
                            int* __restrict__ tbin) {
    int b = blockIdx.x;
    int tid = threadIdx.x;  // 256
    __shared__ unsigned int v[256];
    __shared__ int best;
    __shared__ unsigned int runsh;
    if (tid == 0) { runsh = 0; tbin[b] = 0; }
    __syncthreads();
    for (int c = 255; c >= 0; c--) {
        unsigned int x = hist[b * HBINS + c * 256 + tid];
        if (__syncthreads_or(x != 0) == 0) continue;  // empty chunk
        v[tid] = x;
        __syncthreads();
        // reverse inclusive prefix sum: v[tid] = sum_{t>=tid} x[t]
        for (int o = 1; o < 256; o <<= 1) {
            unsigned int add = (tid + o < 256) ? v[tid + o] : 0u;
            __syncthreads();
            v[tid] += add;
            __syncthreads();
        }
        if (tid == 0) best = -1;
        __syncthreads();
        unsigned int run = runsh;
        if (run + v[tid] >= (unsigned)NMS_K) atomicMax(&best, tid);
        __syncthreads();
        if (best >= 0) {
            if (tid == 0) tbin[b] = c * 256 + best;
            break;  // uniform
        }
        if (tid == 0) runsh = run + v[0];
        __syncthreads();
    }
}

// -------- compact candidates (score>0.05 && bin>=t) as 64-bit keys --------
__global__ void compact_kernel(const float* __restrict__ conf,
                               const int* __restrict__ tbin,
                               unsigned long long* __restrict__ keys,
                               unsigned int* __restrict__ cnt) {
    int p = blockIdx.x * 256 + threadIdx.x;
    int b = blockIdx.y;
    if (p >= NPRI) return;
    const float* c = conf + ((size_t)b * NPRI + p) * 2;
    float c0 = c[0], c1 = c[1];
    float m  = fmaxf(c0, c1);
    float e0 = expf(c0 - m), e1 = expf(c1 - m);
    float s  = e1 / (e0 + e1);
    if (s > 0.05f) {
        unsigned int bits = __float_as_uint(s);
        if ((int)(bits >> 16) >= tbin[b]) {
            unsigned int pos = atomicAdd(&cnt[b], 1u);
            if (pos < SORT_N)
                keys[(size_t)b * SORT_N + pos] =
                    ((unsigned long long)bits << 32) |
                    (unsigned long long)(~(unsigned int)p);
        }
    }
}

// -------- bitonic sort 8192 keys desc; extract top-5000; decode boxes --------
__global__ __launch_bounds__(1024) void sort_decode_kernel(
        const unsigned long long* __restrict__ keys,
        const float* __restrict__ loc, const float* __restrict__ priors,
        float* __restrict__ cscore, float* __restrict__ cbox,
        float* __restrict__ carea) {
    int b = blockIdx.x;
    int tid = threadIdx.x;
    __shared__ unsigned long long k[SORT_N];  // 64 KiB
    for (int i = tid; i < SORT_N; i += 1024) k[i] = keys[(size_t)b * SORT_N + i];
    __syncthreads();
    for (int kk = 2; kk <= SORT_N; kk <<= 1) {
        for (int j = kk >> 1; j > 0; j >>= 1) {
            for (int i = tid; i < SORT_N; i += 1024) {
                int ixj = i ^ j;
                if (ixj > i) {
                    unsigned long long a = k[i], c = k[ixj];
                    bool desc = ((i & kk) == 0);
                    if (desc ? (a < c) : (a > c)) { k[i] = c; k[ixj] = a; }
                }
            }
            __syncthreads();
        }
    }
    for (int r = tid; r < NMS_K; r += 1024) {
        unsigned long long key = k[r];
        float sc; int idx;
        if (key != 0ULL) {
            sc  = __uint_as_float((unsigned int)(key >> 32));
            idx = (int)(~(unsigned int)key);
        } else { sc = -1.0f; idx = 0; }
        cscore[b * NMS_K + r] = sc;
        float x1 = 0.f, y1 = 0.f, x2 = 0.f, y2 = 0.f, ar = 0.f;
        if (key != 0ULL) {
            const float* l  = loc + ((size_t)b * NPRI + idx) * 4;
            const float* pr = priors + (size_t)idx * 4;
            float lx = l[0], ly = l[1], lw = l[2], lh = l[3];
            float pcx = pr[0], pcy = pr[1], pw = pr[2], ph = pr[3];
            // exactly: xy = p_xy + (l_xy*0.1)*p_wh ; wh = p_wh*exp(l_wh*0.2)
            float cx = pcx + (lx * 0.1f) * pw;
            float cy = pcy + (ly * 0.1f) * ph;
            float w  = pw * expf(lw * 0.2f);
            float h  = ph * expf(lh * 0.2f);
            x1 = cx - w * 0.5f;  y1 = cy - h * 0.5f;
            x2 = x1 + w;         y2 = y1 + h;
            ar = (x2 - x1) * (y2 - y1);
        }
        float* cb = cbox + ((size_t)b * NMS_K + r) * 4;
        cb[0] = x1; cb[1] = y1; cb[2] = x2; cb[3] = y2;
        carea[b * NMS_K + r] = ar;
    }
}

// -------- greedy NMS, one block per batch --------
__global__ __launch_bounds__(1024) void nms_kernel(
        const float* __restrict__ cscore, const float* __restrict__ cbox,
        const float* __restrict__ carea, float* __restrict__ out) {
    int b = blockIdx.x;
    int tid = threadIdx.x;
    __shared__ float s[SPAD];
    __shared__ int sh_pick;
    __shared__ int sh_ptr;
    __shared__ int wres[16];
    for (int j = tid; j < SPAD; j += 1024)
        s[j] = (j < NMS_K) ? cscore[b * NMS_K + j] : -1.0f;
    float lx1[5], ly1[5], lx2[5], ly2[5], la[5];
#pragma unroll
    for (int kk = 0; kk < 5; kk++) {
        int j = tid * 5 + kk;
        if (j < NMS_K) {
            const float* cb = cbox + ((size_t)b * NMS_K + j) * 4;
            lx1[kk] = cb[0]; ly1[kk] = cb[1]; lx2[kk] = cb[2]; ly2[kk] = cb[3];
            la[kk]  = carea[b * NMS_K + j];
        } else { lx1[kk] = ly1[kk] = lx2[kk] = ly2[kk] = la[kk] = 0.f; }
    }
    if (tid == 0) sh_ptr = 0;
    __syncthreads();

    for (int r = 0; r < TOPK; r++) {
        int pick;
        for (;;) {  // find first j >= ptr with s[j] > 0 (sorted => argmax)
            int p = sh_ptr;
            int j = p + tid;
            float v = (j < NMS_K) ? s[j] : -1.0f;
            unsigned long long bal = __ballot(v > 0.0f);
            int w = tid >> 6, lane = tid & 63;
            if (lane == 0) wres[w] = bal ? (int)__builtin_ctzll(bal) : (1 << 20);
            __syncthreads();
            if (tid == 0) {
                int bestoff = (1 << 20);
                for (int ww = 0; ww < 16; ww++) {
                    int cand = (wres[ww] == (1 << 20)) ? (1 << 20) : ww * 64 + wres[ww];
                    if (cand < bestoff) bestoff = cand;
                }
                if (bestoff != (1 << 20)) { sh_pick = p + bestoff; sh_ptr = p + bestoff; }
                else if (p + 1024 < NMS_K) { sh_pick = -2; sh_ptr = p + 1024; }
                else sh_pick = -1;
            }
            __syncthreads();
            pick = sh_pick;
            if (pick != -2) break;
        }
        if (pick < 0) break;  // remaining rows stay zero (memset)
        float sc = s[pick];
        const float* pb = cbox + ((size_t)b * NMS_K + pick) * 4;
        float bx1 = pb[0], by1 = pb[1], bx2 = pb[2], by2 = pb[3];
        float ba = carea[b * NMS_K + pick];
        if (tid == 0) {
            float* o = out + (((size_t)b * 2 + 1) * TOPK + r) * 5;
            o[0] = sc; o[1] = bx1; o[2] = by1; o[3] = bx2; o[4] = by2;
        }
        __syncthreads();  // everyone has read s[pick] before owner clears it
#pragma unroll
        for (int kk = 0; kk < 5; kk++) {
            int j = tid * 5 + kk;
            float sj = s[j];
            if (sj > 0.0f) {
                float xx1 = fmaxf(lx1[kk], bx1);
                float yy1 = fmaxf(ly1[kk], by1);
                float xx2 = fminf(lx2[kk], bx2);
                float yy2 = fminf(ly2[kk], by2);
                float iw = fmaxf(xx2 - xx1, 0.0f);
                float ih = fmaxf(yy2 - yy1, 0.0f);
                float inter = iw * ih;
                float uni = (la[kk] - inter) + ba;   // area_j - inter + area_i
                float iou = inter / uni;             // IEEE div, matches ref
                if (iou > 0.3f || j == pick) s[j] = -1.0f;
            }
        }
        __syncthreads();
    }
}

extern "C" void kernel_launch(void* const* d_in, const int* in_sizes, int n_in,
                              void* d_out, int out_size, void* d_ws, size_t ws_size,
                              hipStream_t stream) {
    const float* loc    = (const float*)d_in[0];
    const float* conf   = (const float*)d_in[1];
    const float* priors = (const float*)d_in[2];
    float* out = (float*)d_out;

    char* ws = (char*)d_ws;
    size_t off = 0;
    unsigned int* hist = (unsigned int*)(ws + off);        off += (size_t)BATCH * HBINS * 4;   // 2 MiB
    unsigned long long* keys = (unsigned long long*)(ws + off); off += (size_t)BATCH * SORT_N * 8; // 512 KiB
    unsigned int* cnt = (unsigned int*)(ws + off);         off += 256;
    int* tbin = (int*)(ws + off);                          off += 256;
    float* cscore = (float*)(ws + off);                    off += (size_t)BATCH * NMS_K * 4;
    float* cbox   = (float*)(ws + off);                    off += (size_t)BATCH * NMS_K * 16;
    float* carea  = (float*)(ws + off);                    off += (size_t)BATCH * NMS_K * 4;

    // zero hist + keys + cnt in one shot (contiguous prefix), and the output
    size_t zero_bytes = (size_t)BATCH * HBINS * 4 + (size_t)BATCH * SORT_N * 8 + 256;
    hipMemsetAsync(d_ws, 0, zero_bytes, stream);
    hipMemsetAsync(d_out, 0, (size_t)out_size * 4, stream);

    dim3 gpp((NPRI + 255) / 256, BATCH);
    score_hist_kernel<<<gpp, 256, 0, stream>>>(conf, hist);
    scan_kernel<<<BATCH, 256, 0, stream>>>(hist, tbin);
    compact_kernel<<<gpp, 256, 0, stream>>>(conf, tbin, keys, cnt);
    sort_decode_kernel<<<BATCH, 1024, 0, stream>>>(keys, loc, priors, cscore, cbox, carea);
    nms_kernel<<<BATCH, 1024, 0, stream>>>(cscore, cbox, carea, out);
}

// Round 2
// 877.546 us; speedup vs baseline: 2.0309x; 2.0309x over previous
//
#include <hip/hip_runtime.h>
#include <stdint.h>

#pragma clang fp contract(off)

#define NPRI   136500
#define BATCH  8
#define NMS_K  5000
#define TOPK   750
#define SORT_N 8192
#define HBINS  1024      // top16 float bits of s in (0.05,1] span [0x3D4C,0x3F80]
#define HOFF   0x3D40
#define MWORDS 79        // ceil(5000/64)
#define MPAD   80

// -------- softmax score + per-block LDS histogram of top-16 bits --------
__global__ __launch_bounds__(256) void score_hist_kernel(
        const float* __restrict__ conf, unsigned int* __restrict__ hist) {
    int b = blockIdx.y;
    __shared__ unsigned int h[HBINS];
    for (int i = threadIdx.x; i < HBINS; i += 256) h[i] = 0;
    __syncthreads();
    for (int p = blockIdx.x * 256 + threadIdx.x; p < NPRI; p += 64 * 256) {
        float2 c = ((const float2*)conf)[(size_t)b * NPRI + p];
        float m  = fmaxf(c.x, c.y);
        float e0 = expf(c.x - m), e1 = expf(c.y - m);
        float s  = e1 / (e0 + e1);
        if (s > 0.05f) {
            int bin = (int)(__float_as_uint(s) >> 16) - HOFF;
            bin = min(max(bin, 0), HBINS - 1);
            atomicAdd(&h[bin], 1u);
        }
    }
    __syncthreads();
    for (int i = threadIdx.x; i < HBINS; i += 256) {
        unsigned int v = h[i];
        if (v) atomicAdd(&hist[b * HBINS + i], v);
    }
}

// -------- threshold bin t: largest t with count(bins >= t) >= NMS_K --------
__global__ __launch_bounds__(1024) void scan_kernel(
        const unsigned int* __restrict__ hist, int* __restrict__ tbin) {
    int b = blockIdx.x, t = threadIdx.x;
    __shared__ unsigned int v[HBINS];
    __shared__ int best;
    v[t] = hist[b * HBINS + t];
    if (t == 0) best = 0;
    __syncthreads();
    for (int o = 1; o < HBINS; o <<= 1) {   // reverse inclusive prefix sum
        unsigned int add = (t + o < HBINS) ? v[t + o] : 0u;
        __syncthreads();
        v[t] += add;
        __syncthreads();
    }
    if (v[t] >= (unsigned)NMS_K) atomicMax(&best, t);
    __syncthreads();
    if (t == 0) tbin[b] = best;
}

// -------- compact candidates (score>0.05 && bin>=t) as 64-bit keys --------
__global__ __launch_bounds__(256) void compact_kernel(
        const float* __restrict__ conf, const int* __restrict__ tbin,
        unsigned long long* __restrict__ keys, unsigned int* __restrict__ cnt) {
    int p = blockIdx.x * 256 + threadIdx.x;
    int b = blockIdx.y;
    if (p >= NPRI) return;
    float2 c = ((const float2*)conf)[(size_t)b * NPRI + p];
    float m  = fmaxf(c.x, c.y);
    float e0 = expf(c.x - m), e1 = expf(c.y - m);
    float s  = e1 / (e0 + e1);
    if (s > 0.05f) {
        unsigned int bits = __float_as_uint(s);
        int bin = (int)(bits >> 16) - HOFF;
        bin = min(max(bin, 0), HBINS - 1);
        if (bin >= tbin[b]) {
            unsigned int pos = atomicAdd(&cnt[b], 1u);
            if (pos < SORT_N)
                keys[(size_t)b * SORT_N + pos] =
                    ((unsigned long long)bits << 32) |
                    (unsigned long long)(~(unsigned int)p);
        }
    }
}

// -------- bitonic sort 8192 keys desc; extract top-5000; decode boxes --------
__global__ __launch_bounds__(1024) void sort_decode_kernel(
        const unsigned long long* __restrict__ keys,
        const float* __restrict__ loc, const float* __restrict__ priors,
        float* __restrict__ cscore, float* __restrict__ cbox,
        float* __restrict__ carea) {
    int b = blockIdx.x;
    int tid = threadIdx.x;
    __shared__ unsigned long long k[SORT_N];  // 64 KiB
    for (int i = tid; i < SORT_N; i += 1024) k[i] = keys[(size_t)b * SORT_N + i];
    __syncthreads();
    for (int kk = 2; kk <= SORT_N; kk <<= 1) {
        for (int j = kk >> 1; j > 0; j >>= 1) {
            for (int i = tid; i < SORT_N; i += 1024) {
                int ixj = i ^ j;
                if (ixj > i) {
                    unsigned long long a = k[i], c = k[ixj];
                    bool desc = ((i & kk) == 0);
                    if (desc ? (a < c) : (a > c)) { k[i] = c; k[ixj] = a; }
                }
            }
            __syncthreads();
        }
    }
    for (int r = tid; r < NMS_K; r += 1024) {
        unsigned long long key = k[r];
        float sc; int idx;
        if (key != 0ULL) {
            sc  = __uint_as_float((unsigned int)(key >> 32));
            idx = (int)(~(unsigned int)key);
        } else { sc = -1.0f; idx = 0; }
        cscore[b * NMS_K + r] = sc;
        float x1 = 0.f, y1 = 0.f, x2 = 0.f, y2 = 0.f, ar = 0.f;
        if (key != 0ULL) {
            const float* l  = loc + ((size_t)b * NPRI + idx) * 4;
            const float* pr = priors + (size_t)idx * 4;
            float lx = l[0], ly = l[1], lw = l[2], lh = l[3];
            float pcx = pr[0], pcy = pr[1], pw = pr[2], ph = pr[3];
            float cx = pcx + (lx * 0.1f) * pw;
            float cy = pcy + (ly * 0.1f) * ph;
            float w  = pw * expf(lw * 0.2f);
            float h  = ph * expf(lh * 0.2f);
            x1 = cx - w * 0.5f;  y1 = cy - h * 0.5f;
            x2 = x1 + w;         y2 = y1 + h;
            ar = (x2 - x1) * (y2 - y1);
        }
        float* cb = cbox + ((size_t)b * NMS_K + r) * 4;
        cb[0] = x1; cb[1] = y1; cb[2] = x2; cb[3] = y2;
        carea[b * NMS_K + r] = ar;
    }
}

// -------- suppression bitmask build: bit j of row i = (iou(i,j) > 0.3) -----
// row i = "picked" box; union = (area_j - inter) + area_i, exactly as ref.
__global__ __launch_bounds__(256) void maskbuild_kernel(
        const float* __restrict__ cbox, const float* __restrict__ carea,
        unsigned long long* __restrict__ mask) {
    int b = blockIdx.z, t = threadIdx.x;
    int colblk = blockIdx.y;            // 0..78
    int i = blockIdx.x * 256 + t;       // row
    __shared__ float4 cB[64];
    __shared__ float  cA[64];
    if (t < 64) {
        int j = colblk * 64 + t;
        if (j < NMS_K) {
            cB[t] = ((const float4*)cbox)[(size_t)b * NMS_K + j];
            cA[t] = carea[b * NMS_K + j];
        } else {
            cB[t] = make_float4(0.f, 0.f, 0.f, 0.f);
            cA[t] = 0.f;
        }
    }
    __syncthreads();
    if (i >= NMS_K) return;
    float4 rb = ((const float4*)cbox)[(size_t)b * NMS_K + i];
    float  ra = carea[b * NMS_K + i];
    unsigned long long word = 0ull;
#pragma unroll 8
    for (int jj = 0; jj < 64; jj++) {
        float4 c4 = cB[jj];
        float xx1 = fmaxf(c4.x, rb.x);
        float yy1 = fmaxf(c4.y, rb.y);
        float xx2 = fminf(c4.z, rb.z);
        float yy2 = fminf(c4.w, rb.w);
        float iw = fmaxf(xx2 - xx1, 0.0f);
        float ih = fmaxf(yy2 - yy1, 0.0f);
        float inter = iw * ih;
        float uni = (cA[jj] - inter) + ra;   // (area_j - inter) + area_i
        float iou = inter / uni;             // IEEE div, matches ref
        if (iou > 0.3f) word |= (1ull << jj);
    }
    mask[((size_t)b * NMS_K + i) * MPAD + colblk] = word;
}

// -------- greedy scan over the bitmask: one wave per batch --------
__global__ __launch_bounds__(64) void maskscan_kernel(
        const float* __restrict__ cscore, const float* __restrict__ cbox,
        const unsigned int* __restrict__ cnt,
        const unsigned long long* __restrict__ mask,
        float* __restrict__ out) {
    int b = blockIdx.x, lane = threadIdx.x;
    int nv = min((int)cnt[b], NMS_K);
    unsigned long long supp0 = 0ull, supp1 = 0ull;  // lane owns words lane, 64+lane
    int emitted = 0;
    for (int w = 0; w < MWORDS && emitted < TOPK; w++) {
        int base = w * 64;
        if (base >= nv) break;
        unsigned long long valid =
            (nv - base >= 64) ? ~0ull : ((1ull << (nv - base)) - 1ull);
        unsigned long long sw = (w < 64) ? __shfl(supp0, w) : __shfl(supp1, w - 64);
        unsigned long long alive = valid & ~sw;
        while (alive && emitted < TOPK) {
            int bit = __builtin_ctzll(alive);
            int i = base + bit;
            if (lane < 5) {
                float v = (lane == 0) ? cscore[b * NMS_K + i]
                                      : cbox[((size_t)b * NMS_K + i) * 4 + lane - 1];
                out[(((size_t)b * 2 + 1) * TOPK + emitted) * 5 + lane] = v;
            }
            const unsigned long long* row = mask + ((size_t)b * NMS_K + i) * MPAD;
            unsigned long long m0 = row[lane];
            unsigned long long m1 = (lane < MWORDS - 64) ? row[64 + lane] : 0ull;
            supp0 |= m0; supp1 |= m1;
            unsigned long long rw = (w < 64) ? __shfl(m0, w) : __shfl(m1, w - 64);
            alive &= ~rw;
            alive &= ~(1ull << bit);
            emitted++;
        }
    }
}

extern "C" void kernel_launch(void* const* d_in, const int* in_sizes, int n_in,
                              void* d_out, int out_size, void* d_ws, size_t ws_size,
                              hipStream_t stream) {
    const float* loc    = (const float*)d_in[0];
    const float* conf   = (const float*)d_in[1];
    const float* priors = (const float*)d_in[2];
    float* out = (float*)d_out;

    char* ws = (char*)d_ws;
    size_t off = 0;
    unsigned int* hist = (unsigned int*)(ws + off);             off += (size_t)BATCH * HBINS * 4;   // 32 KiB
    unsigned long long* keys = (unsigned long long*)(ws + off); off += (size_t)BATCH * SORT_N * 8;  // 512 KiB
    unsigned int* cnt = (unsigned int*)(ws + off);              off += 256;
    size_t zero_bytes = off;                                    // hist + keys + cnt
    int* tbin = (int*)(ws + off);                               off += 256;
    float* cscore = (float*)(ws + off);                         off += (size_t)BATCH * NMS_K * 4;
    float* cbox   = (float*)(ws + off);                         off += (size_t)BATCH * NMS_K * 16;
    float* carea  = (float*)(ws + off);                         off += (size_t)BATCH * NMS_K * 4;
    unsigned long long* mask = (unsigned long long*)(ws + off); off += (size_t)BATCH * NMS_K * MPAD * 8; // 25.6 MB

    hipMemsetAsync(d_ws, 0, zero_bytes, stream);
    hipMemsetAsync(d_out, 0, (size_t)out_size * 4, stream);

    score_hist_kernel<<<dim3(64, BATCH), 256, 0, stream>>>(conf, hist);
    scan_kernel<<<BATCH, HBINS, 0, stream>>>(hist, tbin);
    compact_kernel<<<dim3((NPRI + 255) / 256, BATCH), 256, 0, stream>>>(conf, tbin, keys, cnt);
    sort_decode_kernel<<<BATCH, 1024, 0, stream>>>(keys, loc, priors, cscore, cbox, carea);
    maskbuild_kernel<<<dim3(20, MWORDS, BATCH), 256, 0, stream>>>(cbox, carea, mask);
    maskscan_kernel<<<BATCH, 64, 0, stream>>>(cscore, cbox, cnt, mask, out);
}

// Round 3
// 644.529 us; speedup vs baseline: 2.7651x; 1.3615x over previous
//
#include <hip/hip_runtime.h>
#include <stdint.h>

#pragma clang fp contract(off)

#define NPRI   136500
#define BATCH  8
#define NMS_K  5000
#define NKPAD  5120      // padded picker-row count (mask columns), 20*256
#define TOPK   750
#define SORT_N 8192
#define HBINS  1024      // top16 float bits of s in (0.05,1] span [0x3D4C,0x3F80]
#define HOFF   0x3D40
#define MWORDS 79        // ceil(5000/64)

typedef unsigned long long u64;

__device__ __forceinline__ u64 shfl64(u64 v, int src) {
    int lo = __shfl((int)(unsigned)(v & 0xffffffffull), src);
    int hi = __shfl((int)(unsigned)(v >> 32), src);
    return ((u64)(unsigned)hi << 32) | (u64)(unsigned)lo;
}

// -------- softmax score + per-block LDS histogram of top-16 bits --------
__global__ __launch_bounds__(256) void score_hist_kernel(
        const float* __restrict__ conf, unsigned int* __restrict__ hist) {
    int b = blockIdx.y;
    __shared__ unsigned int h[HBINS];
    for (int i = threadIdx.x; i < HBINS; i += 256) h[i] = 0;
    __syncthreads();
    for (int p = blockIdx.x * 256 + threadIdx.x; p < NPRI; p += 64 * 256) {
        float2 c = ((const float2*)conf)[(size_t)b * NPRI + p];
        float m  = fmaxf(c.x, c.y);
        float e0 = expf(c.x - m), e1 = expf(c.y - m);
        float s  = e1 / (e0 + e1);
        if (s > 0.05f) {
            int bin = (int)(__float_as_uint(s) >> 16) - HOFF;
            bin = min(max(bin, 0), HBINS - 1);
            atomicAdd(&h[bin], 1u);
        }
    }
    __syncthreads();
    for (int i = threadIdx.x; i < HBINS; i += 256) {
        unsigned int v = h[i];
        if (v) atomicAdd(&hist[b * HBINS + i], v);
    }
}

// -------- threshold bin t: largest t with count(bins >= t) >= NMS_K --------
__global__ __launch_bounds__(1024) void scan_kernel(
        const unsigned int* __restrict__ hist, int* __restrict__ tbin) {
    int b = blockIdx.x, t = threadIdx.x;
    __shared__ unsigned int v[HBINS];
    __shared__ int best;
    v[t] = hist[b * HBINS + t];
    if (t == 0) best = 0;
    __syncthreads();
    for (int o = 1; o < HBINS; o <<= 1) {   // reverse inclusive prefix sum
        unsigned int add = (t + o < HBINS) ? v[t + o] : 0u;
        __syncthreads();
        v[t] += add;
        __syncthreads();
    }
    if (v[t] >= (unsigned)NMS_K) atomicMax(&best, t);
    __syncthreads();
    if (t == 0) tbin[b] = best;
}

// -------- compact candidates, one global atomic per block --------
__global__ __launch_bounds__(256) void compact_kernel(
        const float* __restrict__ conf, const int* __restrict__ tbin,
        u64* __restrict__ keys, unsigned int* __restrict__ cnt) {
    int p = blockIdx.x * 256 + threadIdx.x;
    int b = blockIdx.y;
    bool pass = false;
    unsigned int bits = 0;
    if (p < NPRI) {
        float2 c = ((const float2*)conf)[(size_t)b * NPRI + p];
        float m  = fmaxf(c.x, c.y);
        float e0 = expf(c.x - m), e1 = expf(c.y - m);
        float s  = e1 / (e0 + e1);
        if (s > 0.05f) {
            bits = __float_as_uint(s);
            int bin = (int)(bits >> 16) - HOFF;
            bin = min(max(bin, 0), HBINS - 1);
            pass = (bin >= tbin[b]);
        }
    }
    int w = threadIdx.x >> 6, lane = threadIdx.x & 63;
    u64 bal = __ballot(pass);
    int rank = (int)__popcll(bal & ((1ull << lane) - 1ull));
    __shared__ unsigned int woff[4];
    __shared__ unsigned int basesh;
    if (lane == 0) woff[w] = (unsigned)__popcll(bal);
    __syncthreads();
    if (threadIdx.x == 0) {
        unsigned t0 = woff[0], t1 = woff[1], t2 = woff[2], t3 = woff[3];
        unsigned tot = t0 + t1 + t2 + t3;
        basesh = tot ? atomicAdd(&cnt[b], tot) : 0u;
        woff[0] = 0; woff[1] = t0; woff[2] = t0 + t1; woff[3] = t0 + t1 + t2;
    }
    __syncthreads();
    if (pass) {
        unsigned pos = basesh + woff[w] + rank;
        if (pos < SORT_N)
            keys[(size_t)b * SORT_N + pos] =
                ((u64)bits << 32) | (u64)(~(unsigned int)p);
    }
}

// -------- bitonic sort 8192 keys desc; extract top-5000; decode boxes --------
__global__ __launch_bounds__(1024) void sort_decode_kernel(
        const u64* __restrict__ keys, const unsigned int* __restrict__ cnt,
        const float* __restrict__ loc, const float* __restrict__ priors,
        float* __restrict__ cscore, float* __restrict__ cbox,
        float* __restrict__ carea) {
    int b = blockIdx.x;
    int tid = threadIdx.x;
    int n = min((int)cnt[b], SORT_N);
    __shared__ u64 k[SORT_N];  // 64 KiB
    for (int i = tid; i < SORT_N; i += 1024)
        k[i] = (i < n) ? keys[(size_t)b * SORT_N + i] : 0ull;
    __syncthreads();
    for (int kk = 2; kk <= SORT_N; kk <<= 1) {
        for (int j = kk >> 1; j > 0; j >>= 1) {
            for (int i = tid; i < SORT_N; i += 1024) {
                int ixj = i ^ j;
                if (ixj > i) {
                    u64 a = k[i], c = k[ixj];
                    bool desc = ((i & kk) == 0);
                    if (desc ? (a < c) : (a > c)) { k[i] = c; k[ixj] = a; }
                }
            }
            __syncthreads();
        }
    }
    for (int r = tid; r < NMS_K; r += 1024) {
        u64 key = k[r];
        float sc; int idx;
        if (key != 0ull) {
            sc  = __uint_as_float((unsigned int)(key >> 32));
            idx = (int)(~(unsigned int)key);
        } else { sc = -1.0f; idx = 0; }
        cscore[b * NMS_K + r] = sc;
        float x1 = 0.f, y1 = 0.f, x2 = 0.f, y2 = 0.f, ar = 0.f;
        if (key != 0ull) {
            const float* l  = loc + ((size_t)b * NPRI + idx) * 4;
            const float* pr = priors + (size_t)idx * 4;
            float lx = l[0], ly = l[1], lw = l[2], lh = l[3];
            float pcx = pr[0], pcy = pr[1], pw = pr[2], ph = pr[3];
            float cx = pcx + (lx * 0.1f) * pw;
            float cy = pcy + (ly * 0.1f) * ph;
            float wd = pw * expf(lw * 0.2f);
            float ht = ph * expf(lh * 0.2f);
            x1 = cx - wd * 0.5f;  y1 = cy - ht * 0.5f;
            x2 = x1 + wd;         y2 = y1 + ht;
            ar = (x2 - x1) * (y2 - y1);
        }
        float* cb = cbox + ((size_t)b * NMS_K + r) * 4;
        cb[0] = x1; cb[1] = y1; cb[2] = x2; cb[3] = y2;
        carea[b * NMS_K + r] = ar;
    }
}

// -------- transposed suppression mask: Tm[b][word][picker_row] --------
// bit j%64 of Tm[b][j/64][i] = (iou(box_i, box_j) > 0.3), ref fp order.
__global__ __launch_bounds__(256) void maskbuild_kernel(
        const float* __restrict__ cbox, const float* __restrict__ carea,
        u64* __restrict__ Tm) {
    int b = blockIdx.z, t = threadIdx.x;
    int w = blockIdx.y;                 // 0..78 word (column block)
    int i = blockIdx.x * 256 + t;       // picker row, 0..5119
    __shared__ float4 cB[64];
    __shared__ float  cA[64];
    if (t < 64) {
        int j = w * 64 + t;
        if (j < NMS_K) {
            cB[t] = ((const float4*)cbox)[(size_t)b * NMS_K + j];
            cA[t] = carea[b * NMS_K + j];
        } else {
            cB[t] = make_float4(0.f, 0.f, 0.f, 0.f);
            cA[t] = 0.f;
        }
    }
    __syncthreads();
    u64 word = 0ull;
    if (i < NMS_K) {
        float4 rb = ((const float4*)cbox)[(size_t)b * NMS_K + i];
        float  ra = carea[b * NMS_K + i];
#pragma unroll 8
        for (int jj = 0; jj < 64; jj++) {
            float4 c4 = cB[jj];
            float xx1 = fmaxf(c4.x, rb.x);
            float yy1 = fmaxf(c4.y, rb.y);
            float xx2 = fminf(c4.z, rb.z);
            float yy2 = fminf(c4.w, rb.w);
            float iw = fmaxf(xx2 - xx1, 0.0f);
            float ih = fmaxf(yy2 - yy1, 0.0f);
            float inter = iw * ih;
            float uni = (cA[jj] - inter) + ra;   // (area_j - inter) + area_i
            float iou = inter / uni;             // IEEE div, matches ref
            if (iou > 0.3f) word |= (1ull << jj);
        }
    }
    Tm[((size_t)(b * MWORDS) + w) * NKPAD + i] = word;  // coalesced
}

// -------- greedy scan: word-batched, one wave per batch --------
__global__ __launch_bounds__(64) void maskscan_kernel(
        const float* __restrict__ cscore, const float* __restrict__ cbox,
        const unsigned int* __restrict__ cnt, const u64* __restrict__ Tm,
        float* __restrict__ out) {
    int b = blockIdx.x, lane = threadIdx.x;
    int nv = min((int)cnt[b], NMS_K);
    const u64* TB = Tm + (size_t)b * MWORDS * NKPAD;
    u64 supp0 = 0ull, supp1 = 0ull;     // lane owns words lane, 64+lane
    int emitted = 0;
    u64 Dnext = TB[lane];               // diag block of word 0 (coalesced)
    for (int w = 0; w < MWORDS; w++) {
        int base = w * 64;
        if (base >= nv || emitted >= TOPK) break;
        u64 D = Dnext;                  // lane j = word w of row (base+j)
        int wn = (w + 1 < MWORDS) ? w + 1 : w;
        Dnext = TB[(size_t)wn * NKPAD + (wn * 64 + lane)];  // prefetch
        u64 sw = (w < 64) ? shfl64(supp0, w) : shfl64(supp1, w - 64);
        int rem = nv - base;
        u64 valid = (rem >= 64) ? ~0ull : ((1ull << rem) - 1ull);
        u64 alive = valid & ~sw;
        if (!alive) continue;
        // serial chain through the diagonal block (registers + shfl only)
        u64 pickmask = 0ull;
        int room = TOPK - emitted;
        while (alive && room) {
            int bit = __builtin_ctzll(alive);
            u64 rw = shfl64(D, bit);
            alive &= ~rw;
            alive &= ~(1ull << bit);
            pickmask |= (1ull << bit);
            room--;
        }
        // batched row-OR + output, groups of 8 independent gathers
        u64 tmp = pickmask;
        int e = emitted;
        int p0 = base + __builtin_ctzll(pickmask);
        while (tmp) {
            int pk[8]; int g = 0;
#pragma unroll
            for (int k = 0; k < 8; k++) {
                if (tmp) { pk[k] = base + __builtin_ctzll(tmp); tmp &= tmp - 1ull; g = k + 1; }
                else pk[k] = p0;        // duplicate: OR is idempotent
            }
            u64 a0[8], a1[8];
#pragma unroll
            for (int k = 0; k < 8; k++) {
                a0[k] = TB[(size_t)lane * NKPAD + pk[k]];
                a1[k] = (lane < MWORDS - 64) ? TB[(size_t)(64 + lane) * NKPAD + pk[k]] : 0ull;
            }
#pragma unroll
            for (int k = 0; k < 8; k++) { supp0 |= a0[k]; supp1 |= a1[k]; }
#pragma unroll
            for (int k = 0; k < 8; k++) {
                if (k < g && lane < 5) {
                    int p = pk[k];
                    float v = (lane == 0) ? cscore[b * NMS_K + p]
                                          : cbox[((size_t)b * NMS_K + p) * 4 + lane - 1];
                    out[(((size_t)b * 2 + 1) * TOPK + (e + k)) * 5 + lane] = v;
                }
            }
            e += g;
        }
        emitted += __popcll(pickmask);
    }
}

extern "C" void kernel_launch(void* const* d_in, const int* in_sizes, int n_in,
                              void* d_out, int out_size, void* d_ws, size_t ws_size,
                              hipStream_t stream) {
    const float* loc    = (const float*)d_in[0];
    const float* conf   = (const float*)d_in[1];
    const float* priors = (const float*)d_in[2];
    float* out = (float*)d_out;

    char* ws = (char*)d_ws;
    size_t off = 0;
    unsigned int* hist = (unsigned int*)(ws + off);   off += (size_t)BATCH * HBINS * 4; // 32 KiB
    unsigned int* cnt  = (unsigned int*)(ws + off);   off += 256;
    size_t zero_bytes = off;                          // hist + cnt only
    int* tbin = (int*)(ws + off);                     off += 256;
    u64* keys = (u64*)(ws + off);                     off += (size_t)BATCH * SORT_N * 8;
    float* cscore = (float*)(ws + off);               off += (size_t)BATCH * NMS_K * 4;
    float* cbox   = (float*)(ws + off);               off += (size_t)BATCH * NMS_K * 16;
    float* carea  = (float*)(ws + off);               off += (size_t)BATCH * NMS_K * 4;
    u64* Tm = (u64*)(ws + off);                       off += (size_t)BATCH * MWORDS * NKPAD * 8; // 25.9 MB

    hipMemsetAsync(d_ws, 0, zero_bytes, stream);
    hipMemsetAsync(d_out, 0, (size_t)out_size * 4, stream);

    score_hist_kernel<<<dim3(64, BATCH), 256, 0, stream>>>(conf, hist);
    scan_kernel<<<BATCH, HBINS, 0, stream>>>(hist, tbin);
    compact_kernel<<<dim3((NPRI + 255) / 256, BATCH), 256, 0, stream>>>(conf, tbin, keys, cnt);
    sort_decode_kernel<<<BATCH, 1024, 0, stream>>>(keys, cnt, loc, priors, cscore, cbox, carea);
    maskbuild_kernel<<<dim3(20, MWORDS, BATCH), 256, 0, stream>>>(cbox, carea, Tm);
    maskscan_kernel<<<BATCH, 64, 0, stream>>>(cscore, cbox, cnt, Tm, out);
}

// Round 4
// 485.958 us; speedup vs baseline: 3.6674x; 1.3263x over previous
//
#include <hip/hip_runtime.h>
#include <stdint.h>

#pragma clang fp contract(off)

#define NPRI   136500
#define BATCH  8
#define NMS_K  5000
#define NKPAD  5120      // padded row count
#define TOPK   750
#define SORT_N 8192
#define HBINS  1024      // top16 float bits of s in (0.05,1] span [0x3D4C,0x3F80]
#define HOFF   0x3D40
#define MROW   80        // u64 words per mask row (79 used, padded)

typedef unsigned long long u64;

__device__ __forceinline__ u64 shfl64(u64 v, int src) {
    int lo = __shfl((int)(unsigned)(v & 0xffffffffull), src);
    int hi = __shfl((int)(unsigned)(v >> 32), src);
    return ((u64)(unsigned)hi << 32) | (u64)(unsigned)lo;
}

// -------- softmax score + per-block LDS histogram of top-16 bits --------
__global__ __launch_bounds__(256) void score_hist_kernel(
        const float* __restrict__ conf, unsigned int* __restrict__ hist) {
    int b = blockIdx.y;
    __shared__ unsigned int h[HBINS];
    for (int i = threadIdx.x; i < HBINS; i += 256) h[i] = 0;
    __syncthreads();
    for (int p = blockIdx.x * 256 + threadIdx.x; p < NPRI; p += 64 * 256) {
        float2 c = ((const float2*)conf)[(size_t)b * NPRI + p];
        float m  = fmaxf(c.x, c.y);
        float e0 = expf(c.x - m), e1 = expf(c.y - m);
        float s  = e1 / (e0 + e1);
        if (s > 0.05f) {
            int bin = (int)(__float_as_uint(s) >> 16) - HOFF;
            bin = min(max(bin, 0), HBINS - 1);
            atomicAdd(&h[bin], 1u);
        }
    }
    __syncthreads();
    for (int i = threadIdx.x; i < HBINS; i += 256) {
        unsigned int v = h[i];
        if (v) atomicAdd(&hist[b * HBINS + i], v);
    }
}

// -------- threshold bin t: largest t with count(bins >= t) >= NMS_K --------
__global__ __launch_bounds__(1024) void scan_kernel(
        const unsigned int* __restrict__ hist, int* __restrict__ tbin) {
    int b = blockIdx.x, t = threadIdx.x;
    __shared__ unsigned int v[HBINS];
    __shared__ int best;
    v[t] = hist[b * HBINS + t];
    if (t == 0) best = 0;
    __syncthreads();
    for (int o = 1; o < HBINS; o <<= 1) {   // reverse inclusive prefix sum
        unsigned int add = (t + o < HBINS) ? v[t + o] : 0u;
        __syncthreads();
        v[t] += add;
        __syncthreads();
    }
    if (v[t] >= (unsigned)NMS_K) atomicMax(&best, t);
    __syncthreads();
    if (t == 0) tbin[b] = best;
}

// -------- compact candidates, one global atomic per block --------
__global__ __launch_bounds__(256) void compact_kernel(
        const float* __restrict__ conf, const int* __restrict__ tbin,
        u64* __restrict__ keys, unsigned int* __restrict__ cnt) {
    int p = blockIdx.x * 256 + threadIdx.x;
    int b = blockIdx.y;
    bool pass = false;
    unsigned int bits = 0;
    if (p < NPRI) {
        float2 c = ((const float2*)conf)[(size_t)b * NPRI + p];
        float m  = fmaxf(c.x, c.y);
        float e0 = expf(c.x - m), e1 = expf(c.y - m);
        float s  = e1 / (e0 + e1);
        if (s > 0.05f) {
            bits = __float_as_uint(s);
            int bin = (int)(bits >> 16) - HOFF;
            bin = min(max(bin, 0), HBINS - 1);
            pass = (bin >= tbin[b]);
        }
    }
    int w = threadIdx.x >> 6, lane = threadIdx.x & 63;
    u64 bal = __ballot(pass);
    int rank = (int)__popcll(bal & ((1ull << lane) - 1ull));
    __shared__ unsigned int woff[4];
    __shared__ unsigned int basesh;
    if (lane == 0) woff[w] = (unsigned)__popcll(bal);
    __syncthreads();
    if (threadIdx.x == 0) {
        unsigned t0 = woff[0], t1 = woff[1], t2 = woff[2], t3 = woff[3];
        unsigned tot = t0 + t1 + t2 + t3;
        basesh = tot ? atomicAdd(&cnt[b], tot) : 0u;
        woff[0] = 0; woff[1] = t0; woff[2] = t0 + t1; woff[3] = t0 + t1 + t2;
    }
    __syncthreads();
    if (pass) {
        unsigned pos = basesh + woff[w] + rank;
        if (pos < SORT_N)
            keys[(size_t)b * SORT_N + pos] =
                ((u64)bits << 32) | (u64)(~(unsigned int)p);
    }
}

// -------- bitonic sort 8192 keys desc; extract top-5000; decode boxes --------
__global__ __launch_bounds__(1024) void sort_decode_kernel(
        const u64* __restrict__ keys, const unsigned int* __restrict__ cnt,
        const float* __restrict__ loc, const float* __restrict__ priors,
        float* __restrict__ cscore, float* __restrict__ cbox,
        float* __restrict__ carea) {
    int b = blockIdx.x;
    int tid = threadIdx.x;
    int n = min((int)cnt[b], SORT_N);
    __shared__ u64 k[SORT_N];  // 64 KiB
    for (int i = tid; i < SORT_N; i += 1024)
        k[i] = (i < n) ? keys[(size_t)b * SORT_N + i] : 0ull;
    __syncthreads();
    for (int kk = 2; kk <= SORT_N; kk <<= 1) {
        for (int j = kk >> 1; j > 0; j >>= 1) {
            for (int i = tid; i < SORT_N; i += 1024) {
                int ixj = i ^ j;
                if (ixj > i) {
                    u64 a = k[i], c = k[ixj];
                    bool desc = ((i & kk) == 0);
                    if (desc ? (a < c) : (a > c)) { k[i] = c; k[ixj] = a; }
                }
            }
            __syncthreads();
        }
    }
    for (int r = tid; r < NMS_K; r += 1024) {
        u64 key = k[r];
        float sc; int idx;
        if (key != 0ull) {
            sc  = __uint_as_float((unsigned int)(key >> 32));
            idx = (int)(~(unsigned int)key);
        } else { sc = -1.0f; idx = 0; }
        cscore[b * NMS_K + r] = sc;
        float x1 = 0.f, y1 = 0.f, x2 = 0.f, y2 = 0.f, ar = 0.f;
        if (key != 0ull) {
            const float* l  = loc + ((size_t)b * NPRI + idx) * 4;
            const float* pr = priors + (size_t)idx * 4;
            float lx = l[0], ly = l[1], lw = l[2], lh = l[3];
            float pcx = pr[0], pcy = pr[1], pw = pr[2], ph = pr[3];
            float cx = pcx + (lx * 0.1f) * pw;
            float cy = pcy + (ly * 0.1f) * ph;
            float wd = pw * expf(lw * 0.2f);
            float ht = ph * expf(lh * 0.2f);
            x1 = cx - wd * 0.5f;  y1 = cy - ht * 0.5f;
            x2 = x1 + wd;         y2 = y1 + ht;
            ar = (x2 - x1) * (y2 - y1);
        }
        float* cb = cbox + ((size_t)b * NMS_K + r) * 4;
        cb[0] = x1; cb[1] = y1; cb[2] = x2; cb[3] = y2;
        carea[b * NMS_K + r] = ar;
    }
}

// -------- row-major UPPER-TRIANGLE suppression mask: M[b][i][w] ----------
// bit j%64 of M[b][i][j/64] = (iou(box_i, box_j) > 0.3) for j > i only.
// Grid: 110 blocks/batch covering only (rowblock, wordgroup) pairs that
// intersect the upper triangle (rb < 2*wg+2).
__global__ __launch_bounds__(256) void maskbuild_kernel(
        const float* __restrict__ cbox, const float* __restrict__ carea,
        u64* __restrict__ M) {
    int b = blockIdx.y;
    int bid = blockIdx.x;               // 0..109
    int wg = 0;                          // cum(wg) = wg*(wg+1)
    while ((wg + 1) * (wg + 2) <= bid) wg++;
    int rb = bid - wg * (wg + 1);
    int t = threadIdx.x;
    int i = rb * 256 + t;
    int w0 = wg * 8;
    __shared__ float sx1[512], sy1[512], sx2[512], sy2[512], sar[512];
    for (int kk = t; kk < 512; kk += 256) {
        int j = w0 * 64 + kk;
        if (j < NMS_K) {
            float4 c4 = ((const float4*)cbox)[(size_t)b * NMS_K + j];
            sx1[kk] = c4.x; sy1[kk] = c4.y; sx2[kk] = c4.z; sy2[kk] = c4.w;
            sar[kk] = carea[b * NMS_K + j];
        } else {
            sx1[kk] = 0.f; sy1[kk] = 0.f; sx2[kk] = 0.f; sy2[kk] = 0.f; sar[kk] = 0.f;
        }
    }
    __syncthreads();
    if (i >= NMS_K) return;
    float4 rbx = ((const float4*)cbox)[(size_t)b * NMS_K + i];
    float  ra  = carea[b * NMS_K + i];
    u64 res[8];
#pragma unroll
    for (int wi = 0; wi < 8; wi++) {
        int w = w0 + wi;
        u64 word = 0ull;
        if (i < 64 * w + 64) {          // word not entirely below diagonal
#pragma unroll 4
            for (int jj = 0; jj < 64; jj++) {
                int kk = wi * 64 + jj;  // all lanes same addr -> LDS broadcast
                float xx1 = fmaxf(sx1[kk], rbx.x);
                float yy1 = fmaxf(sy1[kk], rbx.y);
                float xx2 = fminf(sx2[kk], rbx.z);
                float yy2 = fminf(sy2[kk], rbx.w);
                float iw = fmaxf(xx2 - xx1, 0.0f);
                float ih = fmaxf(yy2 - yy1, 0.0f);
                float inter = iw * ih;
                float uni = (sar[kk] - inter) + ra;  // (area_j - inter) + area_i
                float iou = inter / uni;             // IEEE div, matches ref
                if (iou > 0.3f) word |= (1ull << jj);
            }
            if (i >= 64 * w) {          // diagonal word: keep strictly j > i
                int sh = i - 64 * w;    // 0..63
                word &= (sh == 63) ? 0ull : (~0ull << (sh + 1));
            }
        }
        res[wi] = word;
    }
    u64* dst = M + ((size_t)b * NKPAD + i) * MROW + w0;   // 64 B contiguous
    ((ulonglong2*)dst)[0] = make_ulonglong2(res[0], res[1]);
    ((ulonglong2*)dst)[1] = make_ulonglong2(res[2], res[3]);
    ((ulonglong2*)dst)[2] = make_ulonglong2(res[4], res[5]);
    ((ulonglong2*)dst)[3] = make_ulonglong2(res[6], res[7]);
}

// -------- greedy scan: blocker-skip chain + coalesced row gather ---------
__global__ __launch_bounds__(256) void maskscan_kernel(
        const float* __restrict__ cscore, const float* __restrict__ cbox,
        const unsigned int* __restrict__ cnt, const u64* __restrict__ M,
        float* __restrict__ out) {
    int b = blockIdx.x;
    int tid = threadIdx.x, lane = tid & 63, wv = tid >> 6;
    int nv = min((int)cnt[b], NMS_K);
    const u64* MB = M + (size_t)b * NKPAD * MROW;
    __shared__ unsigned int supp32[2 * MROW];
    __shared__ u64 dbuf[2][64];
    __shared__ int picklist[64];
    __shared__ int npick_sh, emitted_sh;
    for (int i = tid; i < 2 * MROW; i += 256) supp32[i] = 0u;
    if (tid == 0) emitted_sh = 0;
    if (wv == 1) dbuf[0][lane] = MB[(size_t)lane * MROW + 0];  // diag(0)
    __syncthreads();
    int emitted = 0;
    int nwords = (nv + 63) >> 6;
    for (int w = 0; w < nwords; w++) {
        int wn = w + 1;
        u64 dpre = 0ull;                 // wave1: prefetch diag(w+1)
        if (wv == 1 && wn < nwords) {
            int r = wn * 64 + lane;
            if (r < NKPAD) dpre = MB[(size_t)r * MROW + wn];
        }
        if (wv == 0) {
            u64 D   = dbuf[w & 1][lane];
            u64 sup = ((u64)supp32[2 * w + 1] << 32) | (u64)supp32[2 * w];
            int base = w * 64, rem = nv - base;
            u64 valid = (rem >= 64) ? ~0ull : ((1ull << rem) - 1ull);
            u64 alive = valid & ~sup;
            u64 nz = __ballot(D != 0ull);   // rows with in-word suppressions
            u64 pickmask = 0ull;
            while (alive) {
                u64 blockers = alive & nz;
                if (!blockers) { pickmask |= alive; break; }
                int nb = __builtin_ctzll(blockers);
                u64 mle = (nb >= 63) ? ~0ull : ((1ull << (nb + 1)) - 1ull);
                pickmask |= alive & mle;    // free run + the blocker itself
                u64 rw = shfl64(D, nb);     // blocker's in-word suppressions
                alive &= ~mle;
                alive &= ~rw;
            }
            int room = TOPK - emitted;
            int pc = __popcll(pickmask);
            while (pc > room) {             // keep lowest `room` picks
                pickmask &= ~(1ull << (63 - __builtin_clzll(pickmask)));
                pc--;
            }
            if (lane == 0) { npick_sh = pc; emitted_sh = emitted + pc; }
            if ((pickmask >> lane) & 1ull) {
                int rank = (int)__popcll(pickmask & ((1ull << lane) - 1ull));
                picklist[rank] = base + lane;
            }
        }
        __syncthreads();
        int np = npick_sh;
        if (np > 0) {
            // gather picked rows (words w..79, contiguous) -> OR into supp
            for (int pk = wv; pk < np; pk += 4) {
                const u64* row = MB + (size_t)picklist[pk] * MROW;
                for (int wd = w + lane; wd < MROW; wd += 64) {
                    u64 v = row[wd];
                    if (v) {
                        atomicOr(&supp32[2 * wd],     (unsigned int)v);
                        atomicOr(&supp32[2 * wd + 1], (unsigned int)(v >> 32));
                    }
                }
            }
            if (wv == 3) {                  // emit output rows
                for (int kk = lane; kk < np; kk += 64) {
                    int p = picklist[kk];
                    float sc  = cscore[b * NMS_K + p];
                    float4 bx = ((const float4*)cbox)[(size_t)b * NMS_K + p];
                    float* o = out + (((size_t)b * 2 + 1) * TOPK + (emitted + kk)) * 5;
                    o[0] = sc; o[1] = bx.x; o[2] = bx.y; o[3] = bx.z; o[4] = bx.w;
                }
            }
        }
        if (wv == 1 && wn < nwords) dbuf[wn & 1][lane] = dpre;
        __syncthreads();
        emitted = emitted_sh;
        if (emitted >= TOPK) break;
    }
}

extern "C" void kernel_launch(void* const* d_in, const int* in_sizes, int n_in,
                              void* d_out, int out_size, void* d_ws, size_t ws_size,
                              hipStream_t stream) {
    const float* loc    = (const float*)d_in[0];
    const float* conf   = (const float*)d_in[1];
    const float* priors = (const float*)d_in[2];
    float* out = (float*)d_out;

    char* ws = (char*)d_ws;
    size_t off = 0;
    unsigned int* hist = (unsigned int*)(ws + off);   off += (size_t)BATCH * HBINS * 4; // 32 KiB
    unsigned int* cnt  = (unsigned int*)(ws + off);   off += 256;
    size_t zero_bytes = off;                          // hist + cnt only
    int* tbin = (int*)(ws + off);                     off += 256;
    u64* keys = (u64*)(ws + off);                     off += (size_t)BATCH * SORT_N * 8;
    float* cscore = (float*)(ws + off);               off += (size_t)BATCH * NMS_K * 4;
    float* cbox   = (float*)(ws + off);               off += (size_t)BATCH * NMS_K * 16;
    float* carea  = (float*)(ws + off);               off += (size_t)BATCH * NMS_K * 4;
    u64* M = (u64*)(ws + off);                        off += (size_t)BATCH * NKPAD * MROW * 8; // 26.2 MB

    hipMemsetAsync(d_ws, 0, zero_bytes, stream);
    hipMemsetAsync(d_out, 0, (size_t)out_size * 4, stream);

    score_hist_kernel<<<dim3(64, BATCH), 256, 0, stream>>>(conf, hist);
    scan_kernel<<<BATCH, HBINS, 0, stream>>>(hist, tbin);
    compact_kernel<<<dim3((NPRI + 255) / 256, BATCH), 256, 0, stream>>>(conf, tbin, keys, cnt);
    sort_decode_kernel<<<BATCH, 1024, 0, stream>>>(keys, cnt, loc, priors, cscore, cbox, carea);
    maskbuild_kernel<<<dim3(110, BATCH), 256, 0, stream>>>(cbox, carea, M);
    maskscan_kernel<<<BATCH, 256, 0, stream>>>(cscore, cbox, cnt, M, out);
}

// Round 5
// 427.620 us; speedup vs baseline: 4.1677x; 1.1364x over previous
//
#include <hip/hip_runtime.h>
#include <stdint.h>

#pragma clang fp contract(off)

#define NPRI   136500
#define BATCH  8
#define NMS_K  5000
#define NKPAD  5120      // padded row count
#define TOPK   750
#define SORT_N 8192
#define HBINS  1024      // top16 float bits of s in (0.05,1] span [0x3D4C,0x3F80]
#define HOFF   0x3D40
#define MROW   80        // u64 words per mask row (79 used, padded)

typedef unsigned long long u64;

__device__ __forceinline__ u64 shfl64(u64 v, int src) {
    int lo = __shfl((int)(unsigned)(v & 0xffffffffull), src);
    int hi = __shfl((int)(unsigned)(v >> 32), src);
    return ((u64)(unsigned)hi << 32) | (u64)(unsigned)lo;
}

// -------- softmax score + per-block LDS histogram of top-16 bits --------
__global__ __launch_bounds__(256) void score_hist_kernel(
        const float* __restrict__ conf, unsigned int* __restrict__ hist) {
    int b = blockIdx.y;
    __shared__ unsigned int h[HBINS];
    for (int i = threadIdx.x; i < HBINS; i += 256) h[i] = 0;
    __syncthreads();
    for (int p = blockIdx.x * 256 + threadIdx.x; p < NPRI; p += 64 * 256) {
        float2 c = ((const float2*)conf)[(size_t)b * NPRI + p];
        float m  = fmaxf(c.x, c.y);
        float e0 = expf(c.x - m), e1 = expf(c.y - m);
        float s  = e1 / (e0 + e1);
        if (s > 0.05f) {
            int bin = (int)(__float_as_uint(s) >> 16) - HOFF;
            bin = min(max(bin, 0), HBINS - 1);
            atomicAdd(&h[bin], 1u);
        }
    }
    __syncthreads();
    for (int i = threadIdx.x; i < HBINS; i += 256) {
        unsigned int v = h[i];
        if (v) atomicAdd(&hist[b * HBINS + i], v);
    }
}

// -------- threshold bin t: largest t with count(bins >= t) >= NMS_K --------
__global__ __launch_bounds__(1024) void scan_kernel(
        const unsigned int* __restrict__ hist, int* __restrict__ tbin) {
    int b = blockIdx.x, t = threadIdx.x;
    __shared__ unsigned int v[HBINS];
    __shared__ int best;
    v[t] = hist[b * HBINS + t];
    if (t == 0) best = 0;
    __syncthreads();
    for (int o = 1; o < HBINS; o <<= 1) {   // reverse inclusive prefix sum
        unsigned int add = (t + o < HBINS) ? v[t + o] : 0u;
        __syncthreads();
        v[t] += add;
        __syncthreads();
    }
    if (v[t] >= (unsigned)NMS_K) atomicMax(&best, t);
    __syncthreads();
    if (t == 0) tbin[b] = best;
}

// -------- compact candidates, one global atomic per block --------
__global__ __launch_bounds__(256) void compact_kernel(
        const float* __restrict__ conf, const int* __restrict__ tbin,
        u64* __restrict__ keys, unsigned int* __restrict__ cnt) {
    int p = blockIdx.x * 256 + threadIdx.x;
    int b = blockIdx.y;
    bool pass = false;
    unsigned int bits = 0;
    if (p < NPRI) {
        float2 c = ((const float2*)conf)[(size_t)b * NPRI + p];
        float m  = fmaxf(c.x, c.y);
        float e0 = expf(c.x - m), e1 = expf(c.y - m);
        float s  = e1 / (e0 + e1);
        if (s > 0.05f) {
            bits = __float_as_uint(s);
            int bin = (int)(bits >> 16) - HOFF;
            bin = min(max(bin, 0), HBINS - 1);
            pass = (bin >= tbin[b]);
        }
    }
    int w = threadIdx.x >> 6, lane = threadIdx.x & 63;
    u64 bal = __ballot(pass);
    int rank = (int)__popcll(bal & ((1ull << lane) - 1ull));
    __shared__ unsigned int woff[4];
    __shared__ unsigned int basesh;
    if (lane == 0) woff[w] = (unsigned)__popcll(bal);
    __syncthreads();
    if (threadIdx.x == 0) {
        unsigned t0 = woff[0], t1 = woff[1], t2 = woff[2], t3 = woff[3];
        unsigned tot = t0 + t1 + t2 + t3;
        basesh = tot ? atomicAdd(&cnt[b], tot) : 0u;
        woff[0] = 0; woff[1] = t0; woff[2] = t0 + t1; woff[3] = t0 + t1 + t2;
    }
    __syncthreads();
    if (pass) {
        unsigned pos = basesh + woff[w] + rank;
        if (pos < SORT_N)
            keys[(size_t)b * SORT_N + pos] =
                ((u64)bits << 32) | (u64)(~(unsigned int)p);
    }
}

// -------- bitonic stage 1: sort aligned 2048-chunks (levels 2..2048) -------
__global__ __launch_bounds__(512) void sort2k_kernel(
        u64* __restrict__ keys, const unsigned int* __restrict__ cnt) {
    int b = blockIdx.y, c = blockIdx.x;     // chunk 0..3
    int tid = threadIdx.x;
    int n = min((int)cnt[b], SORT_N);
    int base = c * 2048;
    __shared__ u64 k[2048];                 // 16 KiB
    for (int i = tid; i < 2048; i += 512)
        k[i] = (base + i < n) ? keys[(size_t)b * SORT_N + base + i] : 0ull;
    __syncthreads();
    for (int kk = 2; kk <= 2048; kk <<= 1) {
        bool top = (kk == 2048);            // direction from global bit 11
        for (int j = kk >> 1; j > 0; j >>= 1) {
            for (int i = tid; i < 2048; i += 512) {
                int ixj = i ^ j;
                if (ixj > i) {
                    u64 a = k[i], v = k[ixj];
                    bool desc = top ? ((c & 1) == 0) : ((i & kk) == 0);
                    if (desc ? (a < v) : (a > v)) { k[i] = v; k[ixj] = a; }
                }
            }
            __syncthreads();
        }
    }
    for (int i = tid; i < 2048; i += 512)
        keys[(size_t)b * SORT_N + base + i] = k[i];
}

// -------- bitonic stage 2: level 4096 within aligned 4096-chunks ----------
__global__ __launch_bounds__(1024) void sort4k_kernel(u64* __restrict__ keys) {
    int b = blockIdx.y, c = blockIdx.x;     // chunk 0..1
    int tid = threadIdx.x;
    int base = c * 4096;
    bool desc = (c == 0);                   // global bit 12
    __shared__ u64 k[4096];                 // 32 KiB
    for (int i = tid; i < 4096; i += 1024)
        k[i] = keys[(size_t)b * SORT_N + base + i];
    __syncthreads();
    for (int j = 2048; j > 0; j >>= 1) {
        for (int i = tid; i < 4096; i += 1024) {
            int ixj = i ^ j;
            if (ixj > i) {
                u64 a = k[i], v = k[ixj];
                if (desc ? (a < v) : (a > v)) { k[i] = v; k[ixj] = a; }
            }
        }
        __syncthreads();
    }
    for (int i = tid; i < 4096; i += 1024)
        keys[(size_t)b * SORT_N + base + i] = k[i];
}

// -------- bitonic stage 3: level 8192 (whole batch array, descending) -----
__global__ __launch_bounds__(1024) void sort8k_kernel(u64* __restrict__ keys) {
    int b = blockIdx.x;
    int tid = threadIdx.x;
    __shared__ u64 k[SORT_N];               // 64 KiB
    for (int i = tid; i < SORT_N; i += 1024)
        k[i] = keys[(size_t)b * SORT_N + i];
    __syncthreads();
    for (int j = 4096; j > 0; j >>= 1) {
        for (int i = tid; i < SORT_N; i += 1024) {
            int ixj = i ^ j;
            if (ixj > i) {
                u64 a = k[i], v = k[ixj];
                if (a < v) { k[i] = v; k[ixj] = a; }   // descending everywhere
            }
        }
        __syncthreads();
    }
    for (int i = tid; i < SORT_N; i += 1024)
        keys[(size_t)b * SORT_N + i] = k[i];
}

// -------- decode top-5000 sorted keys into score/box/area (160 blocks) ----
__global__ __launch_bounds__(256) void decode_kernel(
        const u64* __restrict__ keys,
        const float* __restrict__ loc, const float* __restrict__ priors,
        float* __restrict__ cscore, float* __restrict__ cbox,
        float* __restrict__ carea) {
    int b = blockIdx.y;
    int r = blockIdx.x * 256 + threadIdx.x;
    if (r >= NMS_K) return;
    u64 key = keys[(size_t)b * SORT_N + r];
    float sc; int idx;
    if (key != 0ull) {
        sc  = __uint_as_float((unsigned int)(key >> 32));
        idx = (int)(~(unsigned int)key);
    } else { sc = -1.0f; idx = 0; }
    cscore[b * NMS_K + r] = sc;
    float x1 = 0.f, y1 = 0.f, x2 = 0.f, y2 = 0.f, ar = 0.f;
    if (key != 0ull) {
        const float* l  = loc + ((size_t)b * NPRI + idx) * 4;
        const float* pr = priors + (size_t)idx * 4;
        float lx = l[0], ly = l[1], lw = l[2], lh = l[3];
        float pcx = pr[0], pcy = pr[1], pw = pr[2], ph = pr[3];
        float cx = pcx + (lx * 0.1f) * pw;
        float cy = pcy + (ly * 0.1f) * ph;
        float wd = pw * expf(lw * 0.2f);
        float ht = ph * expf(lh * 0.2f);
        x1 = cx - wd * 0.5f;  y1 = cy - ht * 0.5f;
        x2 = x1 + wd;         y2 = y1 + ht;
        ar = (x2 - x1) * (y2 - y1);
    }
    float* cb = cbox + ((size_t)b * NMS_K + r) * 4;
    cb[0] = x1; cb[1] = y1; cb[2] = x2; cb[3] = y2;
    carea[b * NMS_K + r] = ar;
}

// -------- row-major UPPER-TRIANGLE suppression mask: M[b][i][w] ----------
// bit j%64 of M[b][i][j/64] = (iou(box_i, box_j) > 0.3) for j > i only.
__global__ __launch_bounds__(256) void maskbuild_kernel(
        const float* __restrict__ cbox, const float* __restrict__ carea,
        u64* __restrict__ M) {
    int b = blockIdx.y;
    int bid = blockIdx.x;               // 0..109
    int wg = 0;                          // cum(wg) = wg*(wg+1)
    while ((wg + 1) * (wg + 2) <= bid) wg++;
    int rb = bid - wg * (wg + 1);
    int t = threadIdx.x;
    int i = rb * 256 + t;
    int w0 = wg * 8;
    __shared__ float sx1[512], sy1[512], sx2[512], sy2[512], sar[512];
    for (int kk = t; kk < 512; kk += 256) {
        int j = w0 * 64 + kk;
        if (j < NMS_K) {
            float4 c4 = ((const float4*)cbox)[(size_t)b * NMS_K + j];
            sx1[kk] = c4.x; sy1[kk] = c4.y; sx2[kk] = c4.z; sy2[kk] = c4.w;
            sar[kk] = carea[b * NMS_K + j];
        } else {
            sx1[kk] = 0.f; sy1[kk] = 0.f; sx2[kk] = 0.f; sy2[kk] = 0.f; sar[kk] = 0.f;
        }
    }
    __syncthreads();
    if (i >= NMS_K) return;
    float4 rbx = ((const float4*)cbox)[(size_t)b * NMS_K + i];
    float  ra  = carea[b * NMS_K + i];
    u64 res[8];
#pragma unroll
    for (int wi = 0; wi < 8; wi++) {
        int w = w0 + wi;
        u64 word = 0ull;
        if (i < 64 * w + 64) {          // word not entirely below diagonal
#pragma unroll 4
            for (int jj = 0; jj < 64; jj++) {
                int kk = wi * 64 + jj;  // all lanes same addr -> LDS broadcast
                float xx1 = fmaxf(sx1[kk], rbx.x);
                float yy1 = fmaxf(sy1[kk], rbx.y);
                float xx2 = fminf(sx2[kk], rbx.z);
                float yy2 = fminf(sy2[kk], rbx.w);
                float iw = fmaxf(xx2 - xx1, 0.0f);
                float ih = fmaxf(yy2 - yy1, 0.0f);
                float inter = iw * ih;
                float uni = (sar[kk] - inter) + ra;  // (area_j - inter) + area_i
                float iou = inter / uni;             // IEEE div, matches ref
                if (iou > 0.3f) word |= (1ull << jj);
            }
            if (i >= 64 * w) {          // diagonal word: keep strictly j > i
                int sh = i - 64 * w;    // 0..63
                word &= (sh == 63) ? 0ull : (~0ull << (sh + 1));
            }
        }
        res[wi] = word;
    }
    u64* dst = M + ((size_t)b * NKPAD + i) * MROW + w0;   // 64 B contiguous
    ((ulonglong2*)dst)[0] = make_ulonglong2(res[0], res[1]);
    ((ulonglong2*)dst)[1] = make_ulonglong2(res[2], res[3]);
    ((ulonglong2*)dst)[2] = make_ulonglong2(res[4], res[5]);
    ((ulonglong2*)dst)[3] = make_ulonglong2(res[6], res[7]);
}

// -------- greedy scan: blocker-skip chain + coalesced row gather ---------
__global__ __launch_bounds__(256) void maskscan_kernel(
        const float* __restrict__ cscore, const float* __restrict__ cbox,
        const unsigned int* __restrict__ cnt, const u64* __restrict__ M,
        float* __restrict__ out) {
    int b = blockIdx.x;
    int tid = threadIdx.x, lane = tid & 63, wv = tid >> 6;
    int nv = min((int)cnt[b], NMS_K);
    const u64* MB = M + (size_t)b * NKPAD * MROW;
    __shared__ unsigned int supp32[2 * MROW];
    __shared__ u64 dbuf[2][64];
    __shared__ int picklist[64];
    __shared__ int npick_sh, emitted_sh;
    for (int i = tid; i < 2 * MROW; i += 256) supp32[i] = 0u;
    if (tid == 0) emitted_sh = 0;
    if (wv == 1) dbuf[0][lane] = MB[(size_t)lane * MROW + 0];  // diag(0)
    __syncthreads();
    int emitted = 0;
    int nwords = (nv + 63) >> 6;
    for (int w = 0; w < nwords; w++) {
        int wn = w + 1;
        u64 dpre = 0ull;                 // wave1: prefetch diag(w+1)
        if (wv == 1 && wn < nwords) {
            int r = wn * 64 + lane;
            if (r < NKPAD) dpre = MB[(size_t)r * MROW + wn];
        }
        if (wv == 0) {
            u64 D   = dbuf[w & 1][lane];
            u64 sup = ((u64)supp32[2 * w + 1] << 32) | (u64)supp32[2 * w];
            int base = w * 64, rem = nv - base;
            u64 valid = (rem >= 64) ? ~0ull : ((1ull << rem) - 1ull);
            u64 alive = valid & ~sup;
            u64 nz = __ballot(D != 0ull);   // rows with in-word suppressions
            u64 pickmask = 0ull;
            while (alive) {
                u64 blockers = alive & nz;
                if (!blockers) { pickmask |= alive; break; }
                int nb = __builtin_ctzll(blockers);
                u64 mle = (nb >= 63) ? ~0ull : ((1ull << (nb + 1)) - 1ull);
                pickmask |= alive & mle;    // free run + the blocker itself
                u64 rw = shfl64(D, nb);     // blocker's in-word suppressions
                alive &= ~mle;
                alive &= ~rw;
            }
            int room = TOPK - emitted;
            int pc = __popcll(pickmask);
            while (pc > room) {             // keep lowest `room` picks
                pickmask &= ~(1ull << (63 - __builtin_clzll(pickmask)));
                pc--;
            }
            if (lane == 0) { npick_sh = pc; emitted_sh = emitted + pc; }
            if ((pickmask >> lane) & 1ull) {
                int rank = (int)__popcll(pickmask & ((1ull << lane) - 1ull));
                picklist[rank] = base + lane;
            }
        }
        __syncthreads();
        int np = npick_sh;
        if (np > 0) {
            // gather picked rows (words w..79, contiguous) -> OR into supp
            for (int pk = wv; pk < np; pk += 4) {
                const u64* row = MB + (size_t)picklist[pk] * MROW;
                for (int wd = w + lane; wd < MROW; wd += 64) {
                    u64 v = row[wd];
                    if (v) {
                        atomicOr(&supp32[2 * wd],     (unsigned int)v);
                        atomicOr(&supp32[2 * wd + 1], (unsigned int)(v >> 32));
                    }
                }
            }
            if (wv == 3) {                  // emit output rows
                for (int kk = lane; kk < np; kk += 64) {
                    int p = picklist[kk];
                    float sc  = cscore[b * NMS_K + p];
                    float4 bx = ((const float4*)cbox)[(size_t)b * NMS_K + p];
                    float* o = out + (((size_t)b * 2 + 1) * TOPK + (emitted + kk)) * 5;
                    o[0] = sc; o[1] = bx.x; o[2] = bx.y; o[3] = bx.z; o[4] = bx.w;
                }
            }
        }
        if (wv == 1 && wn < nwords) dbuf[wn & 1][lane] = dpre;
        __syncthreads();
        emitted = emitted_sh;
        if (emitted >= TOPK) break;
    }
}

extern "C" void kernel_launch(void* const* d_in, const int* in_sizes, int n_in,
                              void* d_out, int out_size, void* d_ws, size_t ws_size,
                              hipStream_t stream) {
    const float* loc    = (const float*)d_in[0];
    const float* conf   = (const float*)d_in[1];
    const float* priors = (const float*)d_in[2];
    float* out = (float*)d_out;

    char* ws = (char*)d_ws;
    size_t off = 0;
    unsigned int* hist = (unsigned int*)(ws + off);   off += (size_t)BATCH * HBINS * 4; // 32 KiB
    unsigned int* cnt  = (unsigned int*)(ws + off);   off += 256;
    size_t zero_bytes = off;                          // hist + cnt only
    int* tbin = (int*)(ws + off);                     off += 256;
    u64* keys = (u64*)(ws + off);                     off += (size_t)BATCH * SORT_N * 8;
    float* cscore = (float*)(ws + off);               off += (size_t)BATCH * NMS_K * 4;
    float* cbox   = (float*)(ws + off);               off += (size_t)BATCH * NMS_K * 16;
    float* carea  = (float*)(ws + off);               off += (size_t)BATCH * NMS_K * 4;
    u64* M = (u64*)(ws + off);                        off += (size_t)BATCH * NKPAD * MROW * 8; // 26.2 MB

    hipMemsetAsync(d_ws, 0, zero_bytes, stream);
    hipMemsetAsync(d_out, 0, (size_t)out_size * 4, stream);

    score_hist_kernel<<<dim3(64, BATCH), 256, 0, stream>>>(conf, hist);
    scan_kernel<<<BATCH, HBINS, 0, stream>>>(hist, tbin);
    compact_kernel<<<dim3((NPRI + 255) / 256, BATCH), 256, 0, stream>>>(conf, tbin, keys, cnt);
    sort2k_kernel<<<dim3(4, BATCH), 512, 0, stream>>>(keys, cnt);
    sort4k_kernel<<<dim3(2, BATCH), 1024, 0, stream>>>(keys);
    sort8k_kernel<<<BATCH, 1024, 0, stream>>>(keys);
    decode_kernel<<<dim3(20, BATCH), 256, 0, stream>>>(keys, loc, priors, cscore, cbox, carea);
    maskbuild_kernel<<<dim3(110, BATCH), 256, 0, stream>>>(cbox, carea, M);
    maskscan_kernel<<<BATCH, 256, 0, stream>>>(cscore, cbox, cnt, M, out);
}

// Round 6
// 391.500 us; speedup vs baseline: 4.5523x; 1.0923x over previous
//
#include <hip/hip_runtime.h>
#include <stdint.h>

#pragma clang fp contract(off)

#define NPRI   136500
#define BATCH  8
#define NMS_K  5000
#define NKPAD  5120      // padded row count
#define TOPK   750
#define SORT_N 8192
#define HBINS  1024      // top16 float bits of s in (0.05,1] span [0x3D4C,0x3F80]
#define HOFF   0x3D40
#define MROW   80        // u64 words per mask row (79 used, padded)

// Exact threshold: RN(inter/uni) > 0.3f  <=>  inter > THR_D * uni (uni>0).
// 0.3f mantissa is even => RN(x) > 0.3f <=> x > 0.3f + ulp/2 = 0.3f + 2^-26.
// THR_D has 26 significand bits; uni has 24 => product exact in double.
#define THR_D (0.300000011920928955078125 + 1.490116119384765625e-8)

typedef unsigned long long u64;

__device__ __forceinline__ u64 shfl64(u64 v, int src) {
    int lo = __shfl((int)(unsigned)(v & 0xffffffffull), src);
    int hi = __shfl((int)(unsigned)(v >> 32), src);
    return ((u64)(unsigned)hi << 32) | (u64)(unsigned)lo;
}

// -------- softmax score + per-block LDS histogram of top-16 bits --------
__global__ __launch_bounds__(256) void score_hist_kernel(
        const float* __restrict__ conf, unsigned int* __restrict__ hist) {
    int b = blockIdx.y;
    __shared__ unsigned int h[HBINS];
    for (int i = threadIdx.x; i < HBINS; i += 256) h[i] = 0;
    __syncthreads();
    for (int p = blockIdx.x * 256 + threadIdx.x; p < NPRI; p += 64 * 256) {
        float2 c = ((const float2*)conf)[(size_t)b * NPRI + p];
        float m  = fmaxf(c.x, c.y);
        float e0 = expf(c.x - m), e1 = expf(c.y - m);
        float s  = e1 / (e0 + e1);
        if (s > 0.05f) {
            int bin = (int)(__float_as_uint(s) >> 16) - HOFF;
            bin = min(max(bin, 0), HBINS - 1);
            atomicAdd(&h[bin], 1u);
        }
    }
    __syncthreads();
    for (int i = threadIdx.x; i < HBINS; i += 256) {
        unsigned int v = h[i];
        if (v) atomicAdd(&hist[b * HBINS + i], v);
    }
}

// -------- threshold bin t: largest t with count(bins >= t) >= NMS_K --------
__global__ __launch_bounds__(1024) void scan_kernel(
        const unsigned int* __restrict__ hist, int* __restrict__ tbin) {
    int b = blockIdx.x, t = threadIdx.x;
    __shared__ unsigned int v[HBINS];
    __shared__ int best;
    v[t] = hist[b * HBINS + t];
    if (t == 0) best = 0;
    __syncthreads();
    for (int o = 1; o < HBINS; o <<= 1) {   // reverse inclusive prefix sum
        unsigned int add = (t + o < HBINS) ? v[t + o] : 0u;
        __syncthreads();
        v[t] += add;
        __syncthreads();
    }
    if (v[t] >= (unsigned)NMS_K) atomicMax(&best, t);
    __syncthreads();
    if (t == 0) tbin[b] = best;
}

// -------- compact candidates, one global atomic per block --------
__global__ __launch_bounds__(256) void compact_kernel(
        const float* __restrict__ conf, const int* __restrict__ tbin,
        u64* __restrict__ keys, unsigned int* __restrict__ cnt) {
    int p = blockIdx.x * 256 + threadIdx.x;
    int b = blockIdx.y;
    bool pass = false;
    unsigned int bits = 0;
    if (p < NPRI) {
        float2 c = ((const float2*)conf)[(size_t)b * NPRI + p];
        float m  = fmaxf(c.x, c.y);
        float e0 = expf(c.x - m), e1 = expf(c.y - m);
        float s  = e1 / (e0 + e1);
        if (s > 0.05f) {
            bits = __float_as_uint(s);
            int bin = (int)(bits >> 16) - HOFF;
            bin = min(max(bin, 0), HBINS - 1);
            pass = (bin >= tbin[b]);
        }
    }
    int w = threadIdx.x >> 6, lane = threadIdx.x & 63;
    u64 bal = __ballot(pass);
    int rank = (int)__popcll(bal & ((1ull << lane) - 1ull));
    __shared__ unsigned int woff[4];
    __shared__ unsigned int basesh;
    if (lane == 0) woff[w] = (unsigned)__popcll(bal);
    __syncthreads();
    if (threadIdx.x == 0) {
        unsigned t0 = woff[0], t1 = woff[1], t2 = woff[2], t3 = woff[3];
        unsigned tot = t0 + t1 + t2 + t3;
        basesh = tot ? atomicAdd(&cnt[b], tot) : 0u;
        woff[0] = 0; woff[1] = t0; woff[2] = t0 + t1; woff[3] = t0 + t1 + t2;
    }
    __syncthreads();
    if (pass) {
        unsigned pos = basesh + woff[w] + rank;
        if (pos < SORT_N)
            keys[(size_t)b * SORT_N + pos] =
                ((u64)bits << 32) | (u64)(~(unsigned int)p);
    }
}

// -------- bitonic stage 1: sort aligned 2048-chunks (levels 2..2048) -------
__global__ __launch_bounds__(512) void sort2k_kernel(
        u64* __restrict__ keys, const unsigned int* __restrict__ cnt) {
    int b = blockIdx.y, c = blockIdx.x;     // chunk 0..3
    int tid = threadIdx.x;
    int n = min((int)cnt[b], SORT_N);
    int base = c * 2048;
    __shared__ u64 k[2048];                 // 16 KiB
    for (int i = tid; i < 2048; i += 512)
        k[i] = (base + i < n) ? keys[(size_t)b * SORT_N + base + i] : 0ull;
    __syncthreads();
    for (int kk = 2; kk <= 2048; kk <<= 1) {
        bool top = (kk == 2048);            // direction from global bit 11
        for (int j = kk >> 1; j > 0; j >>= 1) {
            for (int i = tid; i < 2048; i += 512) {
                int ixj = i ^ j;
                if (ixj > i) {
                    u64 a = k[i], v = k[ixj];
                    bool desc = top ? ((c & 1) == 0) : ((i & kk) == 0);
                    if (desc ? (a < v) : (a > v)) { k[i] = v; k[ixj] = a; }
                }
            }
            __syncthreads();
        }
    }
    for (int i = tid; i < 2048; i += 512)
        keys[(size_t)b * SORT_N + base + i] = k[i];
}

// -------- bitonic stage 2: level 4096 within aligned 4096-chunks ----------
__global__ __launch_bounds__(1024) void sort4k_kernel(u64* __restrict__ keys) {
    int b = blockIdx.y, c = blockIdx.x;     // chunk 0..1
    int tid = threadIdx.x;
    int base = c * 4096;
    bool desc = (c == 0);                   // global bit 12
    __shared__ u64 k[4096];                 // 32 KiB
    for (int i = tid; i < 4096; i += 1024)
        k[i] = keys[(size_t)b * SORT_N + base + i];
    __syncthreads();
    for (int j = 2048; j > 0; j >>= 1) {
        for (int i = tid; i < 4096; i += 1024) {
            int ixj = i ^ j;
            if (ixj > i) {
                u64 a = k[i], v = k[ixj];
                if (desc ? (a < v) : (a > v)) { k[i] = v; k[ixj] = a; }
            }
        }
        __syncthreads();
    }
    for (int i = tid; i < 4096; i += 1024)
        keys[(size_t)b * SORT_N + base + i] = k[i];
}

// -------- bitonic stage 3: level 8192 (whole batch array, descending) -----
__global__ __launch_bounds__(1024) void sort8k_kernel(u64* __restrict__ keys) {
    int b = blockIdx.x;
    int tid = threadIdx.x;
    __shared__ u64 k[SORT_N];               // 64 KiB
    for (int i = tid; i < SORT_N; i += 1024)
        k[i] = keys[(size_t)b * SORT_N + i];
    __syncthreads();
    for (int j = 4096; j > 0; j >>= 1) {
        for (int i = tid; i < SORT_N; i += 1024) {
            int ixj = i ^ j;
            if (ixj > i) {
                u64 a = k[i], v = k[ixj];
                if (a < v) { k[i] = v; k[ixj] = a; }   // descending everywhere
            }
        }
        __syncthreads();
    }
    for (int i = tid; i < SORT_N; i += 1024)
        keys[(size_t)b * SORT_N + i] = k[i];
}

// -------- decode top-5000 sorted keys into score/box/area (160 blocks) ----
__global__ __launch_bounds__(256) void decode_kernel(
        const u64* __restrict__ keys,
        const float* __restrict__ loc, const float* __restrict__ priors,
        float* __restrict__ cscore, float* __restrict__ cbox,
        float* __restrict__ carea) {
    int b = blockIdx.y;
    int r = blockIdx.x * 256 + threadIdx.x;
    if (r >= NMS_K) return;
    u64 key = keys[(size_t)b * SORT_N + r];
    float sc; int idx;
    if (key != 0ull) {
        sc  = __uint_as_float((unsigned int)(key >> 32));
        idx = (int)(~(unsigned int)key);
    } else { sc = -1.0f; idx = 0; }
    cscore[b * NMS_K + r] = sc;
    float x1 = 0.f, y1 = 0.f, x2 = 0.f, y2 = 0.f, ar = 0.f;
    if (key != 0ull) {
        const float* l  = loc + ((size_t)b * NPRI + idx) * 4;
        const float* pr = priors + (size_t)idx * 4;
        float lx = l[0], ly = l[1], lw = l[2], lh = l[3];
        float pcx = pr[0], pcy = pr[1], pw = pr[2], ph = pr[3];
        float cx = pcx + (lx * 0.1f) * pw;
        float cy = pcy + (ly * 0.1f) * ph;
        float wd = pw * expf(lw * 0.2f);
        float ht = ph * expf(lh * 0.2f);
        x1 = cx - wd * 0.5f;  y1 = cy - ht * 0.5f;
        x2 = x1 + wd;         y2 = y1 + ht;
        ar = (x2 - x1) * (y2 - y1);
    }
    float* cb = cbox + ((size_t)b * NMS_K + r) * 4;
    cb[0] = x1; cb[1] = y1; cb[2] = x2; cb[3] = y2;
    carea[b * NMS_K + r] = ar;
}

// -------- row-major UPPER-TRIANGLE suppression mask: M[b][i][w] ----------
// bit j%64 of M[b][i][j/64] = (iou(box_i, box_j) > 0.3) for j > i only.
// Column boxes read with wave-uniform addresses -> SGPR (s_load) operands;
// divide replaced by exact double-multiply test (see THR_D derivation).
__global__ __launch_bounds__(256) void maskbuild_kernel(
        const float* __restrict__ cbox, const float* __restrict__ carea,
        u64* __restrict__ M) {
    int b = blockIdx.y;
    int bid = blockIdx.x;               // 0..109
    int wg = 0;                          // cum(wg) = wg*(wg+1)
    while ((wg + 1) * (wg + 2) <= bid) wg++;
    int rb = bid - wg * (wg + 1);
    int i = rb * 256 + threadIdx.x;
    int w0 = wg * 8;
    if (i >= NMS_K) return;
    const float4* __restrict__ cb_col = (const float4*)cbox + (size_t)b * NMS_K;
    const float*  __restrict__ ca_col = carea + (size_t)b * NMS_K;
    float4 rbx = cb_col[i];
    float  ra  = ca_col[i];
    u64 res[8];
#pragma unroll
    for (int wi = 0; wi < 8; wi++) {
        int w = w0 + wi;
        u64 word = 0ull;
        if (i < 64 * w + 64) {          // word not entirely below diagonal
            int jbase = w << 6;
#pragma unroll 8
            for (int jj = 0; jj < 64; jj++) {
                int jc = jbase + jj;
                if (jc > NMS_K - 1) jc = NMS_K - 1;   // uniform clamp; extra
                float4 c4 = cb_col[jc];               // bits masked by `valid`
                float  aj = ca_col[jc];
                float xx1 = fmaxf(c4.x, rbx.x);
                float yy1 = fmaxf(c4.y, rbx.y);
                float xx2 = fminf(c4.z, rbx.z);
                float yy2 = fminf(c4.w, rbx.w);
                float iw = fmaxf(xx2 - xx1, 0.0f);
                float ih = fmaxf(yy2 - yy1, 0.0f);
                float inter = iw * ih;
                float uni = (aj - inter) + ra;        // (area_j - inter) + area_i
                if ((double)inter > THR_D * (double)uni)
                    word |= (1ull << jj);
            }
            if (i >= 64 * w) {          // diagonal word: keep strictly j > i
                int sh = i - 64 * w;    // 0..63
                word &= (sh == 63) ? 0ull : (~0ull << (sh + 1));
            }
        }
        res[wi] = word;
    }
    u64* dst = M + ((size_t)b * NKPAD + i) * MROW + w0;   // 64 B contiguous
    ((ulonglong2*)dst)[0] = make_ulonglong2(res[0], res[1]);
    ((ulonglong2*)dst)[1] = make_ulonglong2(res[2], res[3]);
    ((ulonglong2*)dst)[2] = make_ulonglong2(res[4], res[5]);
    ((ulonglong2*)dst)[3] = make_ulonglong2(res[6], res[7]);
}

// -------- greedy scan: blocker-skip chain + coalesced row gather ---------
__global__ __launch_bounds__(512) void maskscan_kernel(
        const float* __restrict__ cscore, const float* __restrict__ cbox,
        const unsigned int* __restrict__ cnt, const u64* __restrict__ M,
        float* __restrict__ out) {
    int b = blockIdx.x;
    int tid = threadIdx.x, lane = tid & 63, wv = tid >> 6;  // 8 waves
    int nv = min((int)cnt[b], NMS_K);
    const u64* MB = M + (size_t)b * NKPAD * MROW;
    __shared__ unsigned int supp32[2 * MROW];
    __shared__ u64 dbuf[2][64];
    __shared__ int picklist[64];
    __shared__ int npick_sh, emitted_sh;
    for (int i = tid; i < 2 * MROW; i += 512) supp32[i] = 0u;
    if (tid == 0) emitted_sh = 0;
    if (wv == 1) dbuf[0][lane] = MB[(size_t)lane * MROW + 0];  // diag(0)
    __syncthreads();
    int emitted = 0;
    int nwords = (nv + 63) >> 6;
    for (int w = 0; w < nwords; w++) {
        int wn = w + 1;
        u64 dpre = 0ull;                 // wave1: prefetch diag(w+1)
        if (wv == 1 && wn < nwords) {
            int r = wn * 64 + lane;
            if (r < NKPAD) dpre = MB[(size_t)r * MROW + wn];
        }
        if (wv == 0) {
            u64 D   = dbuf[w & 1][lane];
            u64 sup = ((u64)supp32[2 * w + 1] << 32) | (u64)supp32[2 * w];
            int base = w * 64, rem = nv - base;
            u64 valid = (rem >= 64) ? ~0ull : ((1ull << rem) - 1ull);
            u64 alive = valid & ~sup;
            u64 nz = __ballot(D != 0ull);   // rows with in-word suppressions
            u64 pickmask = 0ull;
            while (alive) {
                u64 blockers = alive & nz;
                if (!blockers) { pickmask |= alive; break; }
                int nb = __builtin_ctzll(blockers);
                u64 mle = (nb >= 63) ? ~0ull : ((1ull << (nb + 1)) - 1ull);
                pickmask |= alive & mle;    // free run + the blocker itself
                u64 rw = shfl64(D, nb);     // blocker's in-word suppressions
                alive &= ~mle;
                alive &= ~rw;
            }
            int room = TOPK - emitted;
            int pc = __popcll(pickmask);
            while (pc > room) {             // keep lowest `room` picks
                pickmask &= ~(1ull << (63 - __builtin_clzll(pickmask)));
                pc--;
            }
            if (lane == 0) { npick_sh = pc; emitted_sh = emitted + pc; }
            if ((pickmask >> lane) & 1ull) {
                int rank = (int)__popcll(pickmask & ((1ull << lane) - 1ull));
                picklist[rank] = base + lane;
            }
        }
        __syncthreads();
        int np = npick_sh;
        if (np > 0) {
            // gather picked rows (words w..79, contiguous) -> OR into supp
            for (int pk = wv; pk < np; pk += 8) {
                const u64* row = MB + (size_t)picklist[pk] * MROW;
                for (int wd = w + lane; wd < MROW; wd += 64) {
                    u64 v = row[wd];
                    if (v) {
                        atomicOr(&supp32[2 * wd],     (unsigned int)v);
                        atomicOr(&supp32[2 * wd + 1], (unsigned int)(v >> 32));
                    }
                }
            }
            if (wv == 3) {                  // emit output rows
                for (int kk = lane; kk < np; kk += 64) {
                    int p = picklist[kk];
                    float sc  = cscore[b * NMS_K + p];
                    float4 bx = ((const float4*)cbox)[(size_t)b * NMS_K + p];
                    float* o = out + (((size_t)b * 2 + 1) * TOPK + (emitted + kk)) * 5;
                    o[0] = sc; o[1] = bx.x; o[2] = bx.y; o[3] = bx.z; o[4] = bx.w;
                }
            }
        }
        if (wv == 1 && wn < nwords) dbuf[wn & 1][lane] = dpre;
        __syncthreads();
        emitted = emitted_sh;
        if (emitted >= TOPK) break;
    }
}

extern "C" void kernel_launch(void* const* d_in, const int* in_sizes, int n_in,
                              void* d_out, int out_size, void* d_ws, size_t ws_size,
                              hipStream_t stream) {
    const float* loc    = (const float*)d_in[0];
    const float* conf   = (const float*)d_in[1];
    const float* priors = (const float*)d_in[2];
    float* out = (float*)d_out;

    char* ws = (char*)d_ws;
    size_t off = 0;
    unsigned int* hist = (unsigned int*)(ws + off);   off += (size_t)BATCH * HBINS * 4; // 32 KiB
    unsigned int* cnt  = (unsigned int*)(ws + off);   off += 256;
    size_t zero_bytes = off;                          // hist + cnt only
    int* tbin = (int*)(ws + off);                     off += 256;
    u64* keys = (u64*)(ws + off);                     off += (size_t)BATCH * SORT_N * 8;
    float* cscore = (float*)(ws + off);               off += (size_t)BATCH * NMS_K * 4;
    float* cbox   = (float*)(ws + off);               off += (size_t)BATCH * NMS_K * 16;
    float* carea  = (float*)(ws + off);               off += (size_t)BATCH * NMS_K * 4;
    u64* M = (u64*)(ws + off);                        off += (size_t)BATCH * NKPAD * MROW * 8; // 26.2 MB

    hipMemsetAsync(d_ws, 0, zero_bytes, stream);
    hipMemsetAsync(d_out, 0, (size_t)out_size * 4, stream);

    score_hist_kernel<<<dim3(64, BATCH), 256, 0, stream>>>(conf, hist);
    scan_kernel<<<BATCH, HBINS, 0, stream>>>(hist, tbin);
    compact_kernel<<<dim3((NPRI + 255) / 256, BATCH), 256, 0, stream>>>(conf, tbin, keys, cnt);
    sort2k_kernel<<<dim3(4, BATCH), 512, 0, stream>>>(keys, cnt);
    sort4k_kernel<<<dim3(2, BATCH), 1024, 0, stream>>>(keys);
    sort8k_kernel<<<BATCH, 1024, 0, stream>>>(keys);
    decode_kernel<<<dim3(20, BATCH), 256, 0, stream>>>(keys, loc, priors, cscore, cbox, carea);
    maskbuild_kernel<<<dim3(110, BATCH), 256, 0, stream>>>(cbox, carea, M);
    maskscan_kernel<<<BATCH, 512, 0, stream>>>(cscore, cbox, cnt, M, out);
}

// Round 7
// 372.601 us; speedup vs baseline: 4.7832x; 1.0507x over previous
//
#include <hip/hip_runtime.h>
#include <stdint.h>

#pragma clang fp contract(off)

#define NPRI   136500
#define BATCH  8
#define NMS_K  5000
#define NKPAD  5120      // padded row count
#define TOPK   750
#define SORT_N 8192
#define HBINS  1024      // top16 float bits of s in (0.05,1] span [0x3D4C,0x3F80]
#define HOFF   0x3D40
#define MROW   80        // u64 words per mask row (79 used, padded)

// Exact threshold: RN(inter/uni) > 0.3f  <=>  inter > THR_D * uni (uni>0).
// 0.3f mantissa is even => RN(x) > 0.3f <=> x > 0.3f + ulp/2 = 0.3f + 2^-26.
// THR_D has 26 significand bits; uni has 24 => product exact in double.
#define THR_D (0.300000011920928955078125 + 1.490116119384765625e-8)

typedef unsigned long long u64;

__device__ __forceinline__ u64 shfl64(u64 v, int src) {
    int lo = __shfl((int)(unsigned)(v & 0xffffffffull), src);
    int hi = __shfl((int)(unsigned)(v >> 32), src);
    return ((u64)(unsigned)hi << 32) | (u64)(unsigned)lo;
}

// -------- softmax score + per-block LDS histogram of top-16 bits --------
__global__ __launch_bounds__(256) void score_hist_kernel(
        const float* __restrict__ conf, unsigned int* __restrict__ hist) {
    int b = blockIdx.y;
    __shared__ unsigned int h[HBINS];
    for (int i = threadIdx.x; i < HBINS; i += 256) h[i] = 0;
    __syncthreads();
    for (int p = blockIdx.x * 256 + threadIdx.x; p < NPRI; p += 64 * 256) {
        float2 c = ((const float2*)conf)[(size_t)b * NPRI + p];
        float m  = fmaxf(c.x, c.y);
        float e0 = expf(c.x - m), e1 = expf(c.y - m);
        float s  = e1 / (e0 + e1);
        if (s > 0.05f) {
            int bin = (int)(__float_as_uint(s) >> 16) - HOFF;
            bin = min(max(bin, 0), HBINS - 1);
            atomicAdd(&h[bin], 1u);
        }
    }
    __syncthreads();
    for (int i = threadIdx.x; i < HBINS; i += 256) {
        unsigned int v = h[i];
        if (v) atomicAdd(&hist[b * HBINS + i], v);
    }
}

// -------- threshold bin t: largest t with count(bins >= t) >= NMS_K --------
__global__ __launch_bounds__(1024) void scan_kernel(
        const unsigned int* __restrict__ hist, int* __restrict__ tbin) {
    int b = blockIdx.x, t = threadIdx.x;
    __shared__ unsigned int v[HBINS];
    __shared__ int best;
    v[t] = hist[b * HBINS + t];
    if (t == 0) best = 0;
    __syncthreads();
    for (int o = 1; o < HBINS; o <<= 1) {   // reverse inclusive prefix sum
        unsigned int add = (t + o < HBINS) ? v[t + o] : 0u;
        __syncthreads();
        v[t] += add;
        __syncthreads();
    }
    if (v[t] >= (unsigned)NMS_K) atomicMax(&best, t);
    __syncthreads();
    if (t == 0) tbin[b] = best;
}

// -------- compact candidates, one global atomic per block --------
__global__ __launch_bounds__(256) void compact_kernel(
        const float* __restrict__ conf, const int* __restrict__ tbin,
        u64* __restrict__ keys, unsigned int* __restrict__ cnt) {
    int p = blockIdx.x * 256 + threadIdx.x;
    int b = blockIdx.y;
    bool pass = false;
    unsigned int bits = 0;
    if (p < NPRI) {
        float2 c = ((const float2*)conf)[(size_t)b * NPRI + p];
        float m  = fmaxf(c.x, c.y);
        float e0 = expf(c.x - m), e1 = expf(c.y - m);
        float s  = e1 / (e0 + e1);
        if (s > 0.05f) {
            bits = __float_as_uint(s);
            int bin = (int)(bits >> 16) - HOFF;
            bin = min(max(bin, 0), HBINS - 1);
            pass = (bin >= tbin[b]);
        }
    }
    int w = threadIdx.x >> 6, lane = threadIdx.x & 63;
    u64 bal = __ballot(pass);
    int rank = (int)__popcll(bal & ((1ull << lane) - 1ull));
    __shared__ unsigned int woff[4];
    __shared__ unsigned int basesh;
    if (lane == 0) woff[w] = (unsigned)__popcll(bal);
    __syncthreads();
    if (threadIdx.x == 0) {
        unsigned t0 = woff[0], t1 = woff[1], t2 = woff[2], t3 = woff[3];
        unsigned tot = t0 + t1 + t2 + t3;
        basesh = tot ? atomicAdd(&cnt[b], tot) : 0u;
        woff[0] = 0; woff[1] = t0; woff[2] = t0 + t1; woff[3] = t0 + t1 + t2;
    }
    __syncthreads();
    if (pass) {
        unsigned pos = basesh + woff[w] + rank;
        if (pos < SORT_N)
            keys[(size_t)b * SORT_N + pos] =
                ((u64)bits << 32) | (u64)(~(unsigned int)p);
    }
}

// -------- bitonic stage 1: sort aligned 2048-chunks (levels 2..2048) -------
__global__ __launch_bounds__(512) void sort2k_kernel(
        u64* __restrict__ keys, const unsigned int* __restrict__ cnt) {
    int b = blockIdx.y, c = blockIdx.x;     // chunk 0..3
    int tid = threadIdx.x;
    int n = min((int)cnt[b], SORT_N);
    int base = c * 2048;
    __shared__ u64 k[2048];                 // 16 KiB
    for (int i = tid; i < 2048; i += 512)
        k[i] = (base + i < n) ? keys[(size_t)b * SORT_N + base + i] : 0ull;
    __syncthreads();
    for (int kk = 2; kk <= 2048; kk <<= 1) {
        bool top = (kk == 2048);            // direction from global bit 11
        for (int j = kk >> 1; j > 0; j >>= 1) {
            for (int i = tid; i < 2048; i += 512) {
                int ixj = i ^ j;
                if (ixj > i) {
                    u64 a = k[i], v = k[ixj];
                    bool desc = top ? ((c & 1) == 0) : ((i & kk) == 0);
                    if (desc ? (a < v) : (a > v)) { k[i] = v; k[ixj] = a; }
                }
            }
            __syncthreads();
        }
    }
    for (int i = tid; i < 2048; i += 512)
        keys[(size_t)b * SORT_N + base + i] = k[i];
}

// -------- bitonic stages 2+3 fused: levels 4096 and 8192 in one block -----
__global__ __launch_bounds__(1024) void sort48_kernel(u64* __restrict__ keys) {
    int b = blockIdx.x;
    int tid = threadIdx.x;
    __shared__ u64 k[SORT_N];               // 64 KiB
    for (int i = tid; i < SORT_N; i += 1024)
        k[i] = keys[(size_t)b * SORT_N + i];
    __syncthreads();
    // level 4096: direction from global bit 12 (chunk0 desc, chunk1 asc)
    for (int j = 2048; j > 0; j >>= 1) {
        for (int i = tid; i < SORT_N; i += 1024) {
            int ixj = i ^ j;
            if (ixj > i) {
                u64 a = k[i], v = k[ixj];
                bool desc = (i & 4096) == 0;
                if (desc ? (a < v) : (a > v)) { k[i] = v; k[ixj] = a; }
            }
        }
        __syncthreads();
    }
    // level 8192: descending everywhere
    for (int j = 4096; j > 0; j >>= 1) {
        for (int i = tid; i < SORT_N; i += 1024) {
            int ixj = i ^ j;
            if (ixj > i) {
                u64 a = k[i], v = k[ixj];
                if (a < v) { k[i] = v; k[ixj] = a; }
            }
        }
        __syncthreads();
    }
    for (int i = tid; i < SORT_N; i += 1024)
        keys[(size_t)b * SORT_N + i] = k[i];
}

// -------- decode top-5000 sorted keys into score/box/area (160 blocks) ----
__global__ __launch_bounds__(256) void decode_kernel(
        const u64* __restrict__ keys,
        const float* __restrict__ loc, const float* __restrict__ priors,
        float* __restrict__ cscore, float* __restrict__ cbox,
        float* __restrict__ carea) {
    int b = blockIdx.y;
    int r = blockIdx.x * 256 + threadIdx.x;
    if (r >= NMS_K) return;
    u64 key = keys[(size_t)b * SORT_N + r];
    float sc; int idx;
    if (key != 0ull) {
        sc  = __uint_as_float((unsigned int)(key >> 32));
        idx = (int)(~(unsigned int)key);
    } else { sc = -1.0f; idx = 0; }
    cscore[b * NMS_K + r] = sc;
    float x1 = 0.f, y1 = 0.f, x2 = 0.f, y2 = 0.f, ar = 0.f;
    if (key != 0ull) {
        const float* l  = loc + ((size_t)b * NPRI + idx) * 4;
        const float* pr = priors + (size_t)idx * 4;
        float lx = l[0], ly = l[1], lw = l[2], lh = l[3];
        float pcx = pr[0], pcy = pr[1], pw = pr[2], ph = pr[3];
        float cx = pcx + (lx * 0.1f) * pw;
        float cy = pcy + (ly * 0.1f) * ph;
        float wd = pw * expf(lw * 0.2f);
        float ht = ph * expf(lh * 0.2f);
        x1 = cx - wd * 0.5f;  y1 = cy - ht * 0.5f;
        x2 = x1 + wd;         y2 = y1 + ht;
        ar = (x2 - x1) * (y2 - y1);
    }
    float* cb = cbox + ((size_t)b * NMS_K + r) * 4;
    cb[0] = x1; cb[1] = y1; cb[2] = x2; cb[3] = y2;
    carea[b * NMS_K + r] = ar;
}

// -------- row-major UPPER-TRIANGLE suppression mask: M[b][i][w] ----------
// bit j%64 of M[b][i][j/64] = (iou(box_i, box_j) > 0.3) for j > i only.
// 4-word (256-col) groups: grid 20x20x8, keep blocks with rb <= wgq
// (210 useful blocks/batch -> ~6.6 waves/SIMD for latency hiding).
__global__ __launch_bounds__(256) void maskbuild_kernel(
        const float* __restrict__ cbox, const float* __restrict__ carea,
        u64* __restrict__ M) {
    int b   = blockIdx.z;
    int wgq = blockIdx.y;               // word group: words wgq*4 .. wgq*4+3
    int rb  = blockIdx.x;               // row block
    if (rb > wgq) return;               // entirely below diagonal
    int i = rb * 256 + threadIdx.x;
    int w0 = wgq * 4;
    if (i >= NMS_K) return;
    const float4* __restrict__ cb_col = (const float4*)cbox + (size_t)b * NMS_K;
    const float*  __restrict__ ca_col = carea + (size_t)b * NMS_K;
    float4 rbx = cb_col[i];
    float  ra  = ca_col[i];
    u64 res[4];
#pragma unroll
    for (int wi = 0; wi < 4; wi++) {
        int w = w0 + wi;
        u64 word = 0ull;
        if (i < 64 * w + 64) {          // word not entirely below diagonal
            int jbase = w << 6;
#pragma unroll 8
            for (int jj = 0; jj < 64; jj++) {
                int jc = jbase + jj;
                if (jc > NMS_K - 1) jc = NMS_K - 1;   // uniform clamp; extra
                float4 c4 = cb_col[jc];               // bits masked by `valid`
                float  aj = ca_col[jc];
                float xx1 = fmaxf(c4.x, rbx.x);
                float yy1 = fmaxf(c4.y, rbx.y);
                float xx2 = fminf(c4.z, rbx.z);
                float yy2 = fminf(c4.w, rbx.w);
                float iw = fmaxf(xx2 - xx1, 0.0f);
                float ih = fmaxf(yy2 - yy1, 0.0f);
                float inter = iw * ih;
                float uni = (aj - inter) + ra;        // (area_j - inter) + area_i
                if ((double)inter > THR_D * (double)uni)
                    word |= (1ull << jj);
            }
            if (i >= 64 * w) {          // diagonal word: keep strictly j > i
                int sh = i - 64 * w;    // 0..63
                word &= (sh == 63) ? 0ull : (~0ull << (sh + 1));
            }
        }
        res[wi] = word;
    }
    u64* dst = M + ((size_t)b * NKPAD + i) * MROW + w0;   // 32 B contiguous
    ((ulonglong2*)dst)[0] = make_ulonglong2(res[0], res[1]);
    ((ulonglong2*)dst)[1] = make_ulonglong2(res[2], res[3]);
}

// -------- greedy scan: blocker-skip chain + coalesced row gather ---------
__global__ __launch_bounds__(512) void maskscan_kernel(
        const float* __restrict__ cscore, const float* __restrict__ cbox,
        const unsigned int* __restrict__ cnt, const u64* __restrict__ M,
        float* __restrict__ out) {
    int b = blockIdx.x;
    int tid = threadIdx.x, lane = tid & 63, wv = tid >> 6;  // 8 waves
    int nv = min((int)cnt[b], NMS_K);
    const u64* MB = M + (size_t)b * NKPAD * MROW;
    __shared__ unsigned int supp32[2 * MROW];
    __shared__ u64 dbuf[2][64];
    __shared__ int picklist[64];
    __shared__ int npick_sh, emitted_sh;
    for (int i = tid; i < 2 * MROW; i += 512) supp32[i] = 0u;
    if (tid == 0) emitted_sh = 0;
    if (wv == 1) dbuf[0][lane] = MB[(size_t)lane * MROW + 0];  // diag(0)
    __syncthreads();
    int emitted = 0;
    int nwords = (nv + 63) >> 6;
    for (int w = 0; w < nwords; w++) {
        int wn = w + 1;
        u64 dpre = 0ull;                 // wave1: prefetch diag(w+1)
        if (wv == 1 && wn < nwords) {
            int r = wn * 64 + lane;
            if (r < NKPAD) dpre = MB[(size_t)r * MROW + wn];
        }
        if (wv == 0) {
            u64 D   = dbuf[w & 1][lane];
            u64 sup = ((u64)supp32[2 * w + 1] << 32) | (u64)supp32[2 * w];
            int base = w * 64, rem = nv - base;
            u64 valid = (rem >= 64) ? ~0ull : ((1ull << rem) - 1ull);
            u64 alive = valid & ~sup;
            u64 nz = __ballot(D != 0ull);   // rows with in-word suppressions
            u64 pickmask = 0ull;
            while (alive) {
                u64 blockers = alive & nz;
                if (!blockers) { pickmask |= alive; break; }
                int nb = __builtin_ctzll(blockers);
                u64 mle = (nb >= 63) ? ~0ull : ((1ull << (nb + 1)) - 1ull);
                pickmask |= alive & mle;    // free run + the blocker itself
                u64 rw = shfl64(D, nb);     // blocker's in-word suppressions
                alive &= ~mle;
                alive &= ~rw;
            }
            int room = TOPK - emitted;
            int pc = __popcll(pickmask);
            while (pc > room) {             // keep lowest `room` picks
                pickmask &= ~(1ull << (63 - __builtin_clzll(pickmask)));
                pc--;
            }
            if (lane == 0) { npick_sh = pc; emitted_sh = emitted + pc; }
            if ((pickmask >> lane) & 1ull) {
                int rank = (int)__popcll(pickmask & ((1ull << lane) - 1ull));
                picklist[rank] = base + lane;
            }
        }
        __syncthreads();
        int np = npick_sh;
        if (np > 0) {
            // gather picked rows (words w..79, contiguous) -> OR into supp
            for (int pk = wv; pk < np; pk += 8) {
                const u64* row = MB + (size_t)picklist[pk] * MROW;
                for (int wd = w + lane; wd < MROW; wd += 64) {
                    u64 v = row[wd];
                    if (v) {
                        atomicOr(&supp32[2 * wd],     (unsigned int)v);
                        atomicOr(&supp32[2 * wd + 1], (unsigned int)(v >> 32));
                    }
                }
            }
            if (wv == 3) {                  // emit output rows
                for (int kk = lane; kk < np; kk += 64) {
                    int p = picklist[kk];
                    float sc  = cscore[b * NMS_K + p];
                    float4 bx = ((const float4*)cbox)[(size_t)b * NMS_K + p];
                    float* o = out + (((size_t)b * 2 + 1) * TOPK + (emitted + kk)) * 5;
                    o[0] = sc; o[1] = bx.x; o[2] = bx.y; o[3] = bx.z; o[4] = bx.w;
                }
            }
        }
        if (wv == 1 && wn < nwords) dbuf[wn & 1][lane] = dpre;
        __syncthreads();
        emitted = emitted_sh;
        if (emitted >= TOPK) break;
    }
}

extern "C" void kernel_launch(void* const* d_in, const int* in_sizes, int n_in,
                              void* d_out, int out_size, void* d_ws, size_t ws_size,
                              hipStream_t stream) {
    const float* loc    = (const float*)d_in[0];
    const float* conf   = (const float*)d_in[1];
    const float* priors = (const float*)d_in[2];
    float* out = (float*)d_out;

    char* ws = (char*)d_ws;
    size_t off = 0;
    unsigned int* hist = (unsigned int*)(ws + off);   off += (size_t)BATCH * HBINS * 4; // 32 KiB
    unsigned int* cnt  = (unsigned int*)(ws + off);   off += 256;
    size_t zero_bytes = off;                          // hist + cnt only
    int* tbin = (int*)(ws + off);                     off += 256;
    u64* keys = (u64*)(ws + off);                     off += (size_t)BATCH * SORT_N * 8;
    float* cscore = (float*)(ws + off);               off += (size_t)BATCH * NMS_K * 4;
    float* cbox   = (float*)(ws + off);               off += (size_t)BATCH * NMS_K * 16;
    float* carea  = (float*)(ws + off);               off += (size_t)BATCH * NMS_K * 4;
    u64* M = (u64*)(ws + off);                        off += (size_t)BATCH * NKPAD * MROW * 8; // 26.2 MB

    hipMemsetAsync(d_ws, 0, zero_bytes, stream);
    hipMemsetAsync(d_out, 0, (size_t)out_size * 4, stream);

    score_hist_kernel<<<dim3(64, BATCH), 256, 0, stream>>>(conf, hist);
    scan_kernel<<<BATCH, HBINS, 0, stream>>>(hist, tbin);
    compact_kernel<<<dim3((NPRI + 255) / 256, BATCH), 256, 0, stream>>>(conf, tbin, keys, cnt);
    sort2k_kernel<<<dim3(4, BATCH), 512, 0, stream>>>(keys, cnt);
    sort48_kernel<<<BATCH, 1024, 0, stream>>>(keys);
    decode_kernel<<<dim3(20, BATCH), 256, 0, stream>>>(keys, loc, priors, cscore, cbox, carea);
    maskbuild_kernel<<<dim3(20, 20, BATCH), 256, 0, stream>>>(cbox, carea, M);
    maskscan_kernel<<<BATCH, 512, 0, stream>>>(cscore, cbox, cnt, M, out);
}

// Round 8
// 334.650 us; speedup vs baseline: 5.3256x; 1.1134x over previous
//
#include <hip/hip_runtime.h>
#include <stdint.h>

#pragma clang fp contract(off)

#define NPRI   136500
#define BATCH  8
#define NMS_K  5000
#define NKPAD  5120      // padded row count
#define TOPK   750
#define SORT_N 8192
#define HBINS  1024      // top16 float bits of s in (0.05,1] span [0x3D4C,0x3F80]
#define HOFF   0x3D40
#define MROW   80        // u64 words per mask row (79 used, padded)

// Exact threshold: RN(inter/uni) > 0.3f  <=>  inter > THR_D * uni (uni>0).
// 0.3f mantissa is even => RN(x) > 0.3f <=> x > 0.3f + ulp/2 = 0.3f + 2^-26.
// THR_D has 26 significand bits; uni has 24 => product exact in double.
#define THR_D (0.300000011920928955078125 + 1.490116119384765625e-8)

typedef unsigned long long u64;

__device__ __forceinline__ u64 shfl64(u64 v, int src) {
    int lo = __shfl((int)(unsigned)(v & 0xffffffffull), src);
    int hi = __shfl((int)(unsigned)(v >> 32), src);
    return ((u64)(unsigned)hi << 32) | (u64)(unsigned)lo;
}
__device__ __forceinline__ u64 shfl64_xor(u64 v, int m) {
    int lo = __shfl_xor((int)(unsigned)(v & 0xffffffffull), m);
    int hi = __shfl_xor((int)(unsigned)(v >> 32), m);
    return ((u64)(unsigned)hi << 32) | (u64)(unsigned)lo;
}

// -------- softmax score + per-block LDS histogram of top-16 bits --------
__global__ __launch_bounds__(256) void score_hist_kernel(
        const float* __restrict__ conf, unsigned int* __restrict__ hist) {
    int b = blockIdx.y;
    __shared__ unsigned int h[HBINS];
    for (int i = threadIdx.x; i < HBINS; i += 256) h[i] = 0;
    __syncthreads();
    for (int p = blockIdx.x * 256 + threadIdx.x; p < NPRI; p += 64 * 256) {
        float2 c = ((const float2*)conf)[(size_t)b * NPRI + p];
        float m  = fmaxf(c.x, c.y);
        float e0 = expf(c.x - m), e1 = expf(c.y - m);
        float s  = e1 / (e0 + e1);
        if (s > 0.05f) {
            int bin = (int)(__float_as_uint(s) >> 16) - HOFF;
            bin = min(max(bin, 0), HBINS - 1);
            atomicAdd(&h[bin], 1u);
        }
    }
    __syncthreads();
    for (int i = threadIdx.x; i < HBINS; i += 256) {
        unsigned int v = h[i];
        if (v) atomicAdd(&hist[b * HBINS + i], v);
    }
}

// -------- threshold bin t: largest t with count(bins >= t) >= NMS_K --------
__global__ __launch_bounds__(1024) void scan_kernel(
        const unsigned int* __restrict__ hist, int* __restrict__ tbin) {
    int b = blockIdx.x, t = threadIdx.x;
    __shared__ unsigned int v[HBINS];
    __shared__ int best;
    v[t] = hist[b * HBINS + t];
    if (t == 0) best = 0;
    __syncthreads();
    for (int o = 1; o < HBINS; o <<= 1) {   // reverse inclusive prefix sum
        unsigned int add = (t + o < HBINS) ? v[t + o] : 0u;
        __syncthreads();
        v[t] += add;
        __syncthreads();
    }
    if (v[t] >= (unsigned)NMS_K) atomicMax(&best, t);
    __syncthreads();
    if (t == 0) tbin[b] = best;
}

// -------- compact candidates, one global atomic per block --------
__global__ __launch_bounds__(256) void compact_kernel(
        const float* __restrict__ conf, const int* __restrict__ tbin,
        u64* __restrict__ keys, unsigned int* __restrict__ cnt) {
    int p = blockIdx.x * 256 + threadIdx.x;
    int b = blockIdx.y;
    bool pass = false;
    unsigned int bits = 0;
    if (p < NPRI) {
        float2 c = ((const float2*)conf)[(size_t)b * NPRI + p];
        float m  = fmaxf(c.x, c.y);
        float e0 = expf(c.x - m), e1 = expf(c.y - m);
        float s  = e1 / (e0 + e1);
        if (s > 0.05f) {
            bits = __float_as_uint(s);
            int bin = (int)(bits >> 16) - HOFF;
            bin = min(max(bin, 0), HBINS - 1);
            pass = (bin >= tbin[b]);
        }
    }
    int w = threadIdx.x >> 6, lane = threadIdx.x & 63;
    u64 bal = __ballot(pass);
    int rank = (int)__popcll(bal & ((1ull << lane) - 1ull));
    __shared__ unsigned int woff[4];
    __shared__ unsigned int basesh;
    if (lane == 0) woff[w] = (unsigned)__popcll(bal);
    __syncthreads();
    if (threadIdx.x == 0) {
        unsigned t0 = woff[0], t1 = woff[1], t2 = woff[2], t3 = woff[3];
        unsigned tot = t0 + t1 + t2 + t3;
        basesh = tot ? atomicAdd(&cnt[b], tot) : 0u;
        woff[0] = 0; woff[1] = t0; woff[2] = t0 + t1; woff[3] = t0 + t1 + t2;
    }
    __syncthreads();
    if (pass) {
        unsigned pos = basesh + woff[w] + rank;
        if (pos < SORT_N)
            keys[(size_t)b * SORT_N + pos] =
                ((u64)bits << 32) | (u64)(~(unsigned int)p);
    }
}

// -------- bitonic stage 1: sort aligned 2048-chunks (levels 2..2048) -------
__global__ __launch_bounds__(512) void sort2k_kernel(
        u64* __restrict__ keys, const unsigned int* __restrict__ cnt) {
    int b = blockIdx.y, c = blockIdx.x;     // chunk 0..3
    int tid = threadIdx.x;
    int n = min((int)cnt[b], SORT_N);
    int base = c * 2048;
    __shared__ u64 k[2048];                 // 16 KiB
    for (int i = tid; i < 2048; i += 512)
        k[i] = (base + i < n) ? keys[(size_t)b * SORT_N + base + i] : 0ull;
    __syncthreads();
    for (int kk = 2; kk <= 2048; kk <<= 1) {
        bool top = (kk == 2048);            // direction from global bit 11
        for (int j = kk >> 1; j > 0; j >>= 1) {
            for (int i = tid; i < 2048; i += 512) {
                int ixj = i ^ j;
                if (ixj > i) {
                    u64 a = k[i], v = k[ixj];
                    bool desc = top ? ((c & 1) == 0) : ((i & kk) == 0);
                    if (desc ? (a < v) : (a > v)) { k[i] = v; k[ixj] = a; }
                }
            }
            __syncthreads();
        }
    }
    for (int i = tid; i < 2048; i += 512)
        keys[(size_t)b * SORT_N + base + i] = k[i];
}

// -------- bitonic stages 2+3 fused: levels 4096 and 8192 in one block -----
__global__ __launch_bounds__(1024) void sort48_kernel(u64* __restrict__ keys) {
    int b = blockIdx.x;
    int tid = threadIdx.x;
    __shared__ u64 k[SORT_N];               // 64 KiB
    for (int i = tid; i < SORT_N; i += 1024)
        k[i] = keys[(size_t)b * SORT_N + i];
    __syncthreads();
    // level 4096: direction from global bit 12 (chunk0 desc, chunk1 asc)
    for (int j = 2048; j > 0; j >>= 1) {
        for (int i = tid; i < SORT_N; i += 1024) {
            int ixj = i ^ j;
            if (ixj > i) {
                u64 a = k[i], v = k[ixj];
                bool desc = (i & 4096) == 0;
                if (desc ? (a < v) : (a > v)) { k[i] = v; k[ixj] = a; }
            }
        }
        __syncthreads();
    }
    // level 8192: descending everywhere
    for (int j = 4096; j > 0; j >>= 1) {
        for (int i = tid; i < SORT_N; i += 1024) {
            int ixj = i ^ j;
            if (ixj > i) {
                u64 a = k[i], v = k[ixj];
                if (a < v) { k[i] = v; k[ixj] = a; }
            }
        }
        __syncthreads();
    }
    for (int i = tid; i < SORT_N; i += 1024)
        keys[(size_t)b * SORT_N + i] = k[i];
}

// -------- decode top-5000 sorted keys into score/box/area (160 blocks) ----
__global__ __launch_bounds__(256) void decode_kernel(
        const u64* __restrict__ keys,
        const float* __restrict__ loc, const float* __restrict__ priors,
        float* __restrict__ cscore, float* __restrict__ cbox,
        float* __restrict__ carea) {
    int b = blockIdx.y;
    int r = blockIdx.x * 256 + threadIdx.x;
    if (r >= NMS_K) return;
    u64 key = keys[(size_t)b * SORT_N + r];
    float sc; int idx;
    if (key != 0ull) {
        sc  = __uint_as_float((unsigned int)(key >> 32));
        idx = (int)(~(unsigned int)key);
    } else { sc = -1.0f; idx = 0; }
    cscore[b * NMS_K + r] = sc;
    float x1 = 0.f, y1 = 0.f, x2 = 0.f, y2 = 0.f, ar = 0.f;
    if (key != 0ull) {
        const float* l  = loc + ((size_t)b * NPRI + idx) * 4;
        const float* pr = priors + (size_t)idx * 4;
        float lx = l[0], ly = l[1], lw = l[2], lh = l[3];
        float pcx = pr[0], pcy = pr[1], pw = pr[2], ph = pr[3];
        float cx = pcx + (lx * 0.1f) * pw;
        float cy = pcy + (ly * 0.1f) * ph;
        float wd = pw * expf(lw * 0.2f);
        float ht = ph * expf(lh * 0.2f);
        x1 = cx - wd * 0.5f;  y1 = cy - ht * 0.5f;
        x2 = x1 + wd;         y2 = y1 + ht;
        ar = (x2 - x1) * (y2 - y1);
    }
    float* cb = cbox + ((size_t)b * NMS_K + r) * 4;
    cb[0] = x1; cb[1] = y1; cb[2] = x2; cb[3] = y2;
    carea[b * NMS_K + r] = ar;
}

// -------- row-major UPPER-TRIANGLE suppression mask: M[b][i][w] ----------
// 128-thread blocks, grid 40(rb) x 20(wgq) x 8: ~420 useful blocks/batch,
// ~26 waves/CU for latency hiding. bit j%64 of M[b][i][j/64] =
// (iou(box_i,box_j) > 0.3) for j > i only.
__global__ __launch_bounds__(128) void maskbuild_kernel(
        const float* __restrict__ cbox, const float* __restrict__ carea,
        u64* __restrict__ M) {
    int b   = blockIdx.z;
    int wgq = blockIdx.y;               // word group: words wgq*4 .. wgq*4+3
    int rb  = blockIdx.x;               // row block (128 rows)
    if (rb > 2 * wgq + 1) return;       // entirely below diagonal
    int i = rb * 128 + threadIdx.x;
    int w0 = wgq * 4;
    if (i >= NMS_K) return;
    const float4* __restrict__ cb_col = (const float4*)cbox + (size_t)b * NMS_K;
    const float*  __restrict__ ca_col = carea + (size_t)b * NMS_K;
    float4 rbx = cb_col[i];
    float  ra  = ca_col[i];
    u64 res[4];
#pragma unroll
    for (int wi = 0; wi < 4; wi++) {
        int w = w0 + wi;
        u64 word = 0ull;
        if (i < 64 * w + 64) {          // word not entirely below diagonal
            int jbase = w << 6;
#pragma unroll 8
            for (int jj = 0; jj < 64; jj++) {
                int jc = jbase + jj;
                if (jc > NMS_K - 1) jc = NMS_K - 1;   // uniform clamp; extra
                float4 c4 = cb_col[jc];               // bits masked by `valid`
                float  aj = ca_col[jc];
                float xx1 = fmaxf(c4.x, rbx.x);
                float yy1 = fmaxf(c4.y, rbx.y);
                float xx2 = fminf(c4.z, rbx.z);
                float yy2 = fminf(c4.w, rbx.w);
                float iw = fmaxf(xx2 - xx1, 0.0f);
                float ih = fmaxf(yy2 - yy1, 0.0f);
                float inter = iw * ih;
                float uni = (aj - inter) + ra;        // (area_j - inter) + area_i
                if ((double)inter > THR_D * (double)uni)
                    word |= (1ull << jj);
            }
            if (i >= 64 * w) {          // diagonal word: keep strictly j > i
                int sh = i - 64 * w;    // 0..63
                word &= (sh == 63) ? 0ull : (~0ull << (sh + 1));
            }
        }
        res[wi] = word;
    }
    u64* dst = M + ((size_t)b * NKPAD + i) * MROW + w0;   // 32 B contiguous
    ((ulonglong2*)dst)[0] = make_ulonglong2(res[0], res[1]);
    ((ulonglong2*)dst)[1] = make_ulonglong2(res[2], res[3]);
}

// -------- greedy scan, software-pipelined --------
// Phase 1 (concurrent): wave0 runs the pick chain for word w (supp word w
// completed via cross-barrier register loads + shfl butterfly); wave1
// prefetches diag(w+1); waves 2..15 gather words >= w+1 of word-(w-1) picks
// into LDS supp (disjoint from chain's word). Phase 2 (short): wave0 issues
// next-word register loads for this word's picks; wave1 stores dbuf. Output
// emit deferred to one parallel pass at the end.
__global__ __launch_bounds__(1024) void maskscan_kernel(
        const float* __restrict__ cscore, const float* __restrict__ cbox,
        const unsigned int* __restrict__ cnt, const u64* __restrict__ M,
        float* __restrict__ out) {
    int b = blockIdx.x;
    int tid = threadIdx.x, lane = tid & 63, wv = tid >> 6;  // 16 waves
    int nv = min((int)cnt[b], NMS_K);
    const u64* MB = M + (size_t)b * NKPAD * MROW;
    float* outb = out + (size_t)b * 2 * TOPK * 5;
    __shared__ unsigned int supp32[2 * MROW];
    __shared__ u64 dbuf[2][64];
    __shared__ int plist[2][64];
    __shared__ short allp[TOPK];
    __shared__ int npick[2];
    __shared__ int emitted_sh;
    for (int i = tid; i < 2 * TOPK * 5; i += 1024) outb[i] = 0.f;  // zero out
    for (int i = tid; i < 2 * MROW; i += 1024) supp32[i] = 0u;
    if (tid == 0) { npick[0] = 0; npick[1] = 0; emitted_sh = 0; }
    if (wv == 1) dbuf[0][lane] = MB[(size_t)lane * MROW];  // diag(0)
    __syncthreads();
    int emitted = 0;
    int nwords = (nv + 63) >> 6;
    u64 rload = 0ull;     // wave0: word-(w) bits of previous word's picks
    for (int w = 0; w < nwords; w++) {
        int par = w & 1;
        u64 dpre = 0ull;
        if (wv == 1 && w + 1 < nwords)   // prefetch diag(w+1); rows<5056 ok
            dpre = MB[(size_t)((w + 1) * 64 + lane) * MROW + (w + 1)];
        if (wv == 0) {
            u64 D = dbuf[par][lane];
            u64 sup = ((u64)supp32[2 * w + 1] << 32) | (u64)supp32[2 * w];
            u64 x = rload;               // carried loads from phase 2 of w-1
#pragma unroll
            for (int m = 1; m < 64; m <<= 1) x |= shfl64_xor(x, m);
            sup |= x;
            int base = w * 64, rem = nv - base;
            u64 valid = (rem >= 64) ? ~0ull : ((1ull << rem) - 1ull);
            u64 alive = valid & ~sup;
            u64 nz = __ballot(D != 0ull);
            u64 pickmask = 0ull;
            while (alive) {
                u64 blockers = alive & nz;
                if (!blockers) { pickmask |= alive; break; }
                int nb = __builtin_ctzll(blockers);
                u64 mle = (nb >= 63) ? ~0ull : ((1ull << (nb + 1)) - 1ull);
                pickmask |= alive & mle;    // free run + the blocker itself
                u64 rw = shfl64(D, nb);     // blocker's in-word suppressions
                alive &= ~mle;
                alive &= ~rw;
            }
            int room = TOPK - emitted;
            int pc = __popcll(pickmask);
            while (pc > room) {             // keep lowest `room` picks
                pickmask &= ~(1ull << (63 - __builtin_clzll(pickmask)));
                pc--;
            }
            if (lane == 0) { npick[par] = pc; emitted_sh = emitted + pc; }
            if ((pickmask >> lane) & 1ull) {
                int rank = (int)__popcll(pickmask & ((1ull << lane) - 1ull));
                plist[par][rank] = base + lane;
                allp[emitted + rank] = (short)(base + lane);
            }
        } else if (wv >= 2) {
            // gather words >= w+1 of picks(w-1) -> OR into supp (disjoint
            // from chain's word-w reads)
            int pn = npick[par ^ 1];
            for (int pk = wv - 2; pk < pn; pk += 14) {
                const u64* row = MB + (size_t)plist[par ^ 1][pk] * MROW;
                for (int wd = w + 1 + lane; wd < MROW; wd += 64) {
                    u64 v = row[wd];
                    if (v) {
                        atomicOr(&supp32[2 * wd],     (unsigned int)v);
                        atomicOr(&supp32[2 * wd + 1], (unsigned int)(v >> 32));
                    }
                }
            }
        }
        __syncthreads();                   // end phase 1
        int np = npick[par];
        if (wv == 0) {                     // issue next-word loads (cross-
            rload = 0ull;                  // barrier VGPR carry)
            if (lane < np)
                rload = MB[(size_t)plist[par][lane] * MROW + (w + 1)];
        } else if (wv == 1 && w + 1 < nwords) {
            dbuf[(w + 1) & 1][lane] = dpre;
        }
        __syncthreads();                   // end phase 2
        emitted = emitted_sh;
        if (emitted >= TOPK) break;
    }
    // final emit: all picks at once, 16 waves
    for (int t = tid; t < emitted; t += 1024) {
        int p = allp[t];
        float sc  = cscore[b * NMS_K + p];
        float4 bx = ((const float4*)cbox)[(size_t)b * NMS_K + p];
        float* o = outb + (size_t)(TOPK + t) * 5;   // class 1 rows
        o[0] = sc; o[1] = bx.x; o[2] = bx.y; o[3] = bx.z; o[4] = bx.w;
    }
}

extern "C" void kernel_launch(void* const* d_in, const int* in_sizes, int n_in,
                              void* d_out, int out_size, void* d_ws, size_t ws_size,
                              hipStream_t stream) {
    const float* loc    = (const float*)d_in[0];
    const float* conf   = (const float*)d_in[1];
    const float* priors = (const float*)d_in[2];
    float* out = (float*)d_out;

    char* ws = (char*)d_ws;
    size_t off = 0;
    unsigned int* hist = (unsigned int*)(ws + off);   off += (size_t)BATCH * HBINS * 4; // 32 KiB
    unsigned int* cnt  = (unsigned int*)(ws + off);   off += 256;
    size_t zero_bytes = off;                          // hist + cnt only
    int* tbin = (int*)(ws + off);                     off += 256;
    u64* keys = (u64*)(ws + off);                     off += (size_t)BATCH * SORT_N * 8;
    float* cscore = (float*)(ws + off);               off += (size_t)BATCH * NMS_K * 4;
    float* cbox   = (float*)(ws + off);               off += (size_t)BATCH * NMS_K * 16;
    float* carea  = (float*)(ws + off);               off += (size_t)BATCH * NMS_K * 4;
    u64* M = (u64*)(ws + off);                        off += (size_t)BATCH * NKPAD * MROW * 8; // 26.2 MB

    hipMemsetAsync(d_ws, 0, zero_bytes, stream);

    score_hist_kernel<<<dim3(64, BATCH), 256, 0, stream>>>(conf, hist);
    scan_kernel<<<BATCH, HBINS, 0, stream>>>(hist, tbin);
    compact_kernel<<<dim3((NPRI + 255) / 256, BATCH), 256, 0, stream>>>(conf, tbin, keys, cnt);
    sort2k_kernel<<<dim3(4, BATCH), 512, 0, stream>>>(keys, cnt);
    sort48_kernel<<<BATCH, 1024, 0, stream>>>(keys);
    decode_kernel<<<dim3(20, BATCH), 256, 0, stream>>>(keys, loc, priors, cscore, cbox, carea);
    maskbuild_kernel<<<dim3(40, 20, BATCH), 128, 0, stream>>>(cbox, carea, M);
    maskscan_kernel<<<BATCH, 1024, 0, stream>>>(cscore, cbox, cnt, M, out);
}